// Round 2
// baseline (336.026 us; speedup 1.0000x reference)
//
#include <hip/hip_runtime.h>

#define NSEQ 2048
#define DIMM 1024
#define NH   16
#define DH   64

using f32x4 = __attribute__((ext_vector_type(4))) float;
using s16x8 = __attribute__((ext_vector_type(8))) short;
using s16x4 = __attribute__((ext_vector_type(4))) short;

__device__ __forceinline__ short f2bf(float f) {
  union { float f; unsigned u; } a; a.f = f;
  unsigned r = (a.u + 0x7fffu + ((a.u >> 16) & 1u)) >> 16;
  return (short)(unsigned short)r;
}
__device__ __forceinline__ float bf2f(short s) {
  union { float f; unsigned u; } a; a.u = ((unsigned)(unsigned short)s) << 16;
  return a.f;
}

__device__ __forceinline__ void async_lds16(const void* g, void* l) {
  __builtin_amdgcn_global_load_lds(
      (const __attribute__((address_space(1))) void*)g,
      (__attribute__((address_space(3))) void*)l, 16, 0, 0);
}

__device__ __forceinline__ float wave_sum(float v) {
  v += __shfl_xor(v, 1);  v += __shfl_xor(v, 2);  v += __shfl_xor(v, 4);
  v += __shfl_xor(v, 8);  v += __shfl_xor(v, 16); v += __shfl_xor(v, 32);
  return v;
}

// ---------------- transpose + f32->bf16 convert: W (K x N) -> Wt (N x K) ----
__global__ __launch_bounds__(256) void transpose_w(const float* __restrict__ W,
                                                   short* __restrict__ Wt,
                                                   int K, int N) {
  __shared__ float tile[32][33];
  const int n0 = blockIdx.x * 32, k0 = blockIdx.y * 32;
  const int tx = threadIdx.x & 31, ty = threadIdx.x >> 5;   // ty: 0..7
#pragma unroll
  for (int r = 0; r < 32; r += 8)
    tile[ty + r][tx] = W[(size_t)(k0 + ty + r) * N + n0 + tx];
  __syncthreads();
#pragma unroll
  for (int r = 0; r < 32; r += 8)
    Wt[(size_t)(n0 + ty + r) * K + k0 + tx] = f2bf(tile[tx][ty + r]);
}

// ---------------- row LayerNorm over 1024 cols (+optional SiLU) -------------
template <bool SILU, bool OUTBF>
__global__ __launch_bounds__(256) void row_ln_k(const float* __restrict__ in,
                                                const float* __restrict__ gamma,
                                                float* __restrict__ of,
                                                short* __restrict__ ob) {
  const int r = blockIdx.x, t = threadIdx.x;
  float4 x = *(const float4*)(in + (size_t)r * 1024 + t * 4);
  float v[4] = {x.x, x.y, x.z, x.w};
  float s  = v[0] + v[1] + v[2] + v[3];
  float ss = v[0]*v[0] + v[1]*v[1] + v[2]*v[2] + v[3]*v[3];
  s = wave_sum(s); ss = wave_sum(ss);
  __shared__ float rb[8];
  const int w = t >> 6, ln = t & 63;
  if (ln == 0) { rb[w] = s; rb[4 + w] = ss; }
  __syncthreads();
  s  = rb[0] + rb[1] + rb[2] + rb[3];
  ss = rb[4] + rb[5] + rb[6] + rb[7];
  const float mean = s * (1.f / 1024.f);
  const float inv  = rsqrtf(ss * (1.f / 1024.f) - mean * mean + 1e-5f);
  float4 gx = *(const float4*)(gamma + t * 4);
  float gg[4] = {gx.x, gx.y, gx.z, gx.w};
#pragma unroll
  for (int j = 0; j < 4; j++) {
    float y = (v[j] - mean) * inv * gg[j];
    if (SILU) y = y / (1.f + __expf(-y));
    v[j] = y;
  }
  if (OUTBF) {
    s16x4 o;
#pragma unroll
    for (int j = 0; j < 4; j++) o[j] = f2bf(v[j]);
    *(s16x4*)(ob + (size_t)r * 1024 + t * 4) = o;
  } else {
    *(float4*)(of + (size_t)r * 1024 + t * 4) = make_float4(v[0], v[1], v[2], v[3]);
  }
}

// ---------------- bias-MLP layer 0: silu(ln(pos*w0 + b0, g0)), pos = row ----
__global__ __launch_bounds__(256) void layer0_k(const float* __restrict__ w0,
                                                const float* __restrict__ b0,
                                                const float* __restrict__ g0,
                                                short* __restrict__ h0) {
  const int r = blockIdx.x, t = threadIdx.x;
  const float p = (float)r;
  float4 wv = *(const float4*)(w0 + t * 4);
  float4 bv = *(const float4*)(b0 + t * 4);
  float v[4] = {p * wv.x + bv.x, p * wv.y + bv.y, p * wv.z + bv.z, p * wv.w + bv.w};
  float s  = v[0] + v[1] + v[2] + v[3];
  float ss = v[0]*v[0] + v[1]*v[1] + v[2]*v[2] + v[3]*v[3];
  s = wave_sum(s); ss = wave_sum(ss);
  __shared__ float rb[8];
  const int w = t >> 6, ln = t & 63;
  if (ln == 0) { rb[w] = s; rb[4 + w] = ss; }
  __syncthreads();
  s  = rb[0] + rb[1] + rb[2] + rb[3];
  ss = rb[4] + rb[5] + rb[6] + rb[7];
  const float mean = s * (1.f / 1024.f);
  const float inv  = rsqrtf(ss * (1.f / 1024.f) - mean * mean + 1e-5f);
  float4 gx = *(const float4*)(g0 + t * 4);
  float gg[4] = {gx.x, gx.y, gx.z, gx.w};
  s16x4 o;
#pragma unroll
  for (int j = 0; j < 4; j++) {
    float y = (v[j] - mean) * inv * gg[j];
    y = y / (1.f + __expf(-y));
    o[j] = f2bf(y);
  }
  *(s16x4*)(h0 + (size_t)r * 1024 + t * 4) = o;
}

// ---------------- q post: l2norm per 64-group * q_scale -> bf16 -------------
// qkv layout: row stride 1152, q at col h*64
__global__ __launch_bounds__(64) void post_q(const float* __restrict__ qt,
                                             const float* __restrict__ qs,
                                             short* __restrict__ qb) {
  const int g = blockIdx.x, d = threadIdx.x;
  const int r = g >> 4, h = g & 15;
  float v = qt[(size_t)r * 1152 + h * 64 + d];
  float ss = wave_sum(v * v);
  float n = fmaxf(sqrtf(ss), 1e-12f);
  qb[(size_t)g * 64 + d] = f2bf(v / n * qs[d]);
}

// ---------------- kv post: k=l2norm*k_scale -> bf16, v -> v^T bf16 ----------
__global__ __launch_bounds__(128) void post_kv(const float* __restrict__ kvt,
                                               const float* __restrict__ ks,
                                               short* __restrict__ kb,
                                               short* __restrict__ vtb) {
  const int row = blockIdx.x, t = threadIdx.x;
  float v = kvt[(size_t)row * 1152 + 1024 + t];
  if (t < 64) {
    float ss = wave_sum(v * v);
    float n = fmaxf(sqrtf(ss), 1e-12f);
    kb[(size_t)row * 64 + t] = f2bf(v / n * ks[t]);
  } else {
    const int d = t - 64, b_ = row >> 11, i = row & 2047;
    vtb[((size_t)b_ * 64 + d) * NSEQ + i] = f2bf(v);
  }
}

// ---------------- btab: h1 (2048x1024 bf16) @ w2 (1024x16) + b2 -> [16][2048]
__global__ __launch_bounds__(256) void btab_k(const short* __restrict__ h1,
                                              const float* __restrict__ w2,
                                              const float* __restrict__ b2,
                                              float* __restrict__ btab) {
  const int r = blockIdx.x, t = threadIdx.x;
  const int n = t & 15, ck = t >> 4;    // 16 chunks of 64
  float acc = 0.f;
  const short* hrow = h1 + (size_t)r * 1024 + ck * 64;
  const float* wcol = w2 + (size_t)(ck * 64) * 16 + n;
#pragma unroll 8
  for (int k = 0; k < 64; k++) acc += bf2f(hrow[k]) * wcol[k * 16];
  __shared__ float red[256];
  red[t] = acc;
  __syncthreads();
  if (t < 16) {
    float s = 0.f;
#pragma unroll
    for (int c = 0; c < 16; c++) s += red[c * 16 + t];
    btab[(size_t)t * NSEQ + r] = s + b2[t];
  }
}

// ---------------- GEMM: C(MxN f32) = A(MxK bf16) * B^T where Bm is (NxK bf16)
template <bool ADD_BIAS>
__global__ __launch_bounds__(256, 2) void gemm_bt(const short* __restrict__ A,
                                                  const short* __restrict__ Bm,
                                                  float* __restrict__ C,
                                                  const float* __restrict__ bias,
                                                  int M, int N, int K) {
  __shared__ __align__(16) short Al[128 * 32];
  __shared__ __align__(16) short Bl[128 * 32];
  const int tid = threadIdx.x;
  const int lane = tid & 63;
  const int l15 = lane & 15, l4 = lane >> 4;
  const int wid = tid >> 6;
  const int wr = wid >> 1, wc = wid & 1;
  const int rowa0 = blockIdx.x * 128, rowb0 = blockIdx.y * 128;
  f32x4 acc[4][4];
#pragma unroll
  for (int m = 0; m < 4; m++)
#pragma unroll
    for (int n = 0; n < 4; n++) acc[m][n] = (f32x4){0.f, 0.f, 0.f, 0.f};

  const int sr = tid >> 2, sc = (tid & 3) * 8;        // staging row / col
  const short* ga = A  + (size_t)(rowa0 + sr) * K + sc;
  const short* gb = Bm + (size_t)(rowb0 + sr) * K + sc;
  char* la = (char*)Al + wid * 1024;                  // wave-uniform LDS base
  char* lb = (char*)Bl + wid * 1024;

  for (int k0 = 0; k0 < K; k0 += 32) {
    async_lds16(ga + k0,                 la);
    async_lds16(ga + (size_t)64 * K + k0, la + 4096);
    async_lds16(gb + k0,                 lb);
    async_lds16(gb + (size_t)64 * K + k0, lb + 4096);
    __syncthreads();
    s16x8 af[4], bfr[4];
#pragma unroll
    for (int m = 0; m < 4; m++)
      af[m] = *(const s16x8*)&Al[(wr * 64 + m * 16 + l15) * 32 + l4 * 8];
#pragma unroll
    for (int n = 0; n < 4; n++)
      bfr[n] = *(const s16x8*)&Bl[(wc * 64 + n * 16 + l15) * 32 + l4 * 8];
#pragma unroll
    for (int m = 0; m < 4; m++)
#pragma unroll
      for (int n = 0; n < 4; n++)
        acc[m][n] = __builtin_amdgcn_mfma_f32_16x16x32_bf16(af[m], bfr[n], acc[m][n], 0, 0, 0);
    __syncthreads();
  }
#pragma unroll
  for (int n = 0; n < 4; n++) {
    const int col = rowb0 + wc * 64 + n * 16 + l15;
    const float bv = ADD_BIAS ? bias[col] : 0.f;
#pragma unroll
    for (int m = 0; m < 4; m++) {
      const int row = rowa0 + wr * 64 + m * 16 + l4 * 4;
#pragma unroll
      for (int j = 0; j < 4; j++)
        C[(size_t)(row + j) * N + col] = acc[m][n][j] + bv;
    }
  }
}

// ---------------- flash attention, barrier-free per-wave --------------------
// grid: flat 1024; LPT order (largest qtile first). Each wave owns 16 q rows,
// loads K/V fragments straight from global (L2-resident), K prefetched one
// tile ahead. Only wave-private LDS roundtrips (P repack, O store) — no
// __syncthreads in the loop.
__global__ __launch_bounds__(256, 2) void attn_k(const short* __restrict__ q,
                                                 const short* __restrict__ kk,
                                                 const short* __restrict__ vt,
                                                 const float* __restrict__ btab,
                                                 const float* __restrict__ nkv,
                                                 const float* __restrict__ nbias,
                                                 const float* __restrict__ kscale,
                                                 short* __restrict__ aout) {
  __shared__ __align__(16) short Pl[4 * 16 * 64]; // per-wave P, swizzled
  __shared__ __align__(16) float Ob[4 * 16 * 64]; // per-wave O for coalesced store
  __shared__ float nkn[64], nvv[64];

  const int tid = threadIdx.x;
  const int w = tid >> 6, lane = tid & 63;
  const int l15 = lane & 15, l4 = lane >> 4;
  const int bid = blockIdx.x;
  const int b = bid & 1, h = (bid >> 1) & 15, qt = 31 - (bid >> 5);
  const int i0 = qt * 64;
  const int nt = qt + 1;
  const int qrow0 = i0 + w * 16;

  if (w == 0) {
    float kx = nkv[lane];
    float ss = wave_sum(kx * kx);
    float nrm = fmaxf(sqrtf(ss), 1e-12f);
    nkn[lane] = kx / nrm * kscale[lane];
    nvv[lane] = nkv[64 + lane];
  }
  const short* qbase = q + (size_t)(b * NSEQ + qrow0) * DIMM + h * DH;
  s16x8 qf0 = *(const s16x8*)(qbase + (size_t)l15 * DIMM + l4 * 8);
  s16x8 qf1 = *(const s16x8*)(qbase + (size_t)l15 * DIMM + 32 + l4 * 8);
  __syncthreads();

  // null-token init of online softmax
  float sn = 0.f;
#pragma unroll
  for (int j = 0; j < 8; j++)
    sn += bf2f(qf0[j]) * nkn[l4 * 8 + j] + bf2f(qf1[j]) * nkn[32 + l4 * 8 + j];
  sn += __shfl_xor(sn, 16);
  sn += __shfl_xor(sn, 32);
  sn = sn * 8.f + nbias[h];
  float mrow[4], lsum[4];
  f32x4 o[4];
#pragma unroll
  for (int jj = 0; jj < 4; jj++) { mrow[jj] = __shfl(sn, l4 * 4 + jj); lsum[jj] = 1.f; }
#pragma unroll
  for (int dg = 0; dg < 4; dg++) {
    float nv = nvv[dg * 16 + l15];
#pragma unroll
    for (int jj = 0; jj < 4; jj++) o[dg][jj] = nv;
  }

  const float* bth = btab + (size_t)h * NSEQ;
  const short* kbb = kk + (size_t)b * NSEQ * DH;
  const short* vbb = vt + (size_t)b * DH * NSEQ;
  char* pw = (char*)Pl + w * 2048;

  // preload K tile 0 into registers
  s16x8 k0r[4], k1r[4];
#pragma unroll
  for (int kb = 0; kb < 4; kb++) {
    const short* kp = kbb + (size_t)(kb * 16 + l15) * DH + l4 * 8;
    k0r[kb] = *(const s16x8*)kp;
    k1r[kb] = *(const s16x8*)(kp + 32);
  }

  for (int t = 0; t < nt; ++t) {
    const int j0 = t * 64;
    // V fragments for this tile (independent — issue early)
    s16x8 vf[2][4];
#pragma unroll
    for (int kc = 0; kc < 2; kc++)
#pragma unroll
      for (int dg = 0; dg < 4; dg++)
        vf[kc][dg] = *(const s16x8*)(vbb + (size_t)(dg * 16 + l15) * NSEQ +
                                     j0 + (kc * 4 + l4) * 8);
    // prefetch next K tile
    const int jn = (t + 1 < nt) ? j0 + 64 : j0;
    s16x8 kn0[4], kn1[4];
#pragma unroll
    for (int kb = 0; kb < 4; kb++) {
      const short* kp = kbb + (size_t)(jn + kb * 16 + l15) * DH + l4 * 8;
      kn0[kb] = *(const s16x8*)kp;
      kn1[kb] = *(const s16x8*)(kp + 32);
    }
    // QK^T
    f32x4 s[4];
#pragma unroll
    for (int kb = 0; kb < 4; kb++) {
      s[kb] = (f32x4){0.f, 0.f, 0.f, 0.f};
      s[kb] = __builtin_amdgcn_mfma_f32_16x16x32_bf16(qf0, k0r[kb], s[kb], 0, 0, 0);
      s[kb] = __builtin_amdgcn_mfma_f32_16x16x32_bf16(qf1, k1r[kb], s[kb], 0, 0, 0);
    }
    float pm[4] = {-3e38f, -3e38f, -3e38f, -3e38f};
#pragma unroll
    for (int kb = 0; kb < 4; kb++) {
      const int keyg = j0 + kb * 16 + l15;
#pragma unroll
      for (int jj = 0; jj < 4; jj++) {
        const int i = i0 + w * 16 + l4 * 4 + jj;
        const int rel = i - keyg;
        float sv = (rel >= 0) ? (s[kb][jj] * 8.f + bth[rel]) : -3e38f;
        s[kb][jj] = sv;
        pm[jj] = fmaxf(pm[jj], sv);
      }
    }
#pragma unroll
    for (int jj = 0; jj < 4; jj++) {
      pm[jj] = fmaxf(pm[jj], __shfl_xor(pm[jj], 1));
      pm[jj] = fmaxf(pm[jj], __shfl_xor(pm[jj], 2));
      pm[jj] = fmaxf(pm[jj], __shfl_xor(pm[jj], 4));
      pm[jj] = fmaxf(pm[jj], __shfl_xor(pm[jj], 8));
    }
    float al[4], rs[4];
#pragma unroll
    for (int jj = 0; jj < 4; jj++) {
      const float mn = fmaxf(mrow[jj], pm[jj]);
      al[jj] = __expf(mrow[jj] - mn);
      mrow[jj] = mn;
      rs[jj] = 0.f;
    }
#pragma unroll
    for (int kb = 0; kb < 4; kb++)
#pragma unroll
      for (int jj = 0; jj < 4; jj++) {
        const float p = __expf(s[kb][jj] - mrow[jj]);
        s[kb][jj] = p;
        rs[jj] += p;
      }
#pragma unroll
    for (int jj = 0; jj < 4; jj++) {
      rs[jj] += __shfl_xor(rs[jj], 1);
      rs[jj] += __shfl_xor(rs[jj], 2);
      rs[jj] += __shfl_xor(rs[jj], 4);
      rs[jj] += __shfl_xor(rs[jj], 8);
      lsum[jj] = lsum[jj] * al[jj] + rs[jj];
    }
#pragma unroll
    for (int dg = 0; dg < 4; dg++)
#pragma unroll
      for (int jj = 0; jj < 4; jj++) o[dg][jj] *= al[jj];
    // P: C-layout -> swizzled per-wave LDS [row=q][key] (in-wave ordering only)
#pragma unroll
    for (int kb = 0; kb < 4; kb++) {
      const int key = kb * 16 + l15;
#pragma unroll
      for (int jj = 0; jj < 4; jj++) {
        const int row = l4 * 4 + jj;
        *(short*)(pw + row * 128 + (((key >> 3) ^ (row & 7)) << 4) + ((key & 7) << 1)) =
            f2bf(s[kb][jj]);
      }
    }
    // PV
#pragma unroll
    for (int kc = 0; kc < 2; kc++) {
      s16x8 pf = *(const s16x8*)(pw + l15 * 128 + ((((kc << 2) + l4) ^ (l15 & 7)) << 4));
#pragma unroll
      for (int dg = 0; dg < 4; dg++)
        o[dg] = __builtin_amdgcn_mfma_f32_16x16x32_bf16(pf, vf[kc][dg], o[dg], 0, 0, 0);
    }
#pragma unroll
    for (int kb = 0; kb < 4; kb++) { k0r[kb] = kn0[kb]; k1r[kb] = kn1[kb]; }
  }

  float* ob = Ob + w * 1024;
#pragma unroll
  for (int dg = 0; dg < 4; dg++)
#pragma unroll
    for (int jj = 0; jj < 4; jj++)
      ob[(l4 * 4 + jj) * 64 + dg * 16 + l15] = o[dg][jj] / lsum[jj];
  const int orow = lane >> 2, oc = (lane & 3) * 16;
  const float* srcp = ob + orow * 64 + oc;
  s16x8 r0, r1;
#pragma unroll
  for (int j = 0; j < 8; j++) { r0[j] = f2bf(srcp[j]); r1[j] = f2bf(srcp[8 + j]); }
  short* gout = aout + (size_t)(b * NSEQ + i0 + w * 16 + orow) * DIMM + h * DH + oc;
  *(s16x8*)gout = r0;
  *(s16x8*)(gout + 8) = r1;
}

// ---------------------------------------------------------------------------
extern "C" void kernel_launch(void* const* d_in, const int* in_sizes, int n_in,
                              void* d_out, int out_size, void* d_ws, size_t ws_size,
                              hipStream_t stream) {
  const float* x       = (const float*)d_in[0];
  const float* g_norm  = (const float*)d_in[2];
  const float* Wq      = (const float*)d_in[3];
  const float* Wkv     = (const float*)d_in[4];
  const float* q_scale = (const float*)d_in[5];
  const float* k_scale = (const float*)d_in[6];
  const float* null_kv = (const float*)d_in[7];
  const float* nbias   = (const float*)d_in[8];
  const float* w0      = (const float*)d_in[9];
  const float* b0      = (const float*)d_in[10];
  const float* g0      = (const float*)d_in[11];
  const float* w1      = (const float*)d_in[12];
  const float* b1      = (const float*)d_in[13];
  const float* g1      = (const float*)d_in[14];
  const float* w2      = (const float*)d_in[15];
  const float* b2      = (const float*)d_in[16];
  const float* Wout    = (const float*)d_in[17];
  const float* g_out   = (const float*)d_in[18];

  char* p = (char*)d_ws;
  auto alloc = [&](size_t bytes) {
    char* r = p; p += (bytes + 255) & ~(size_t)255; return r;
  };
  short* xn     = (short*)alloc((size_t)4096 * 1024 * 2);
  short* wqkvT  = (short*)alloc((size_t)1152 * 1024 * 2);  // rows 0..1023 Wq^T, 1024..1151 Wkv^T
  short* w1T    = (short*)alloc((size_t)1024 * 1024 * 2);
  short* woT    = (short*)alloc((size_t)1024 * 1024 * 2);
  float* qkvtmp = (float*)alloc((size_t)4096 * 1152 * 4);
  short* qb     = (short*)alloc((size_t)4096 * 1024 * 2);
  short* kbuf   = (short*)alloc((size_t)2 * NSEQ * DH * 2);
  short* vtb    = (short*)alloc((size_t)2 * DH * NSEQ * 2);
  short* h0     = (short*)alloc((size_t)2048 * 1024 * 2);
  short* h1     = (short*)alloc((size_t)2048 * 1024 * 2);
  float* btab   = (float*)alloc((size_t)16 * NSEQ * 4);
  float* h1t  = qkvtmp;        // reuse: qkvtmp consumed by post_q/post_kv first
  float* opre = qkvtmp;        // reuse again after h1t consumed
  short* aout = xn;            // reuse: xn consumed by the input GEMM

  // weight transposes (f32 -> bf16, N x K); Wkv^T stacked under Wq^T
  transpose_w<<<dim3(32, 32), 256, 0, stream>>>(Wq,   wqkvT, 1024, 1024);
  transpose_w<<<dim3(4, 32),  256, 0, stream>>>(Wkv,  wqkvT + (size_t)1024 * 1024, 1024, 128);
  transpose_w<<<dim3(32, 32), 256, 0, stream>>>(w1,   w1T,  1024, 1024);
  transpose_w<<<dim3(32, 32), 256, 0, stream>>>(Wout, woT,  1024, 1024);
  // xn = LN(x) * g_norm  -> bf16
  row_ln_k<false, true><<<4096, 256, 0, stream>>>(x, g_norm, nullptr, xn);
  // fused q+kv projection: N = 1152
  gemm_bt<false><<<dim3(32, 9), 256, 0, stream>>>(xn, wqkvT, qkvtmp, nullptr, 4096, 1152, 1024);
  post_q<<<65536, 64, 0, stream>>>(qkvtmp, q_scale, qb);
  post_kv<<<4096, 128, 0, stream>>>(qkvtmp, k_scale, kbuf, vtb);
  // rel-pos bias MLP (only rel in [0,2047] is ever used)
  layer0_k<<<2048, 256, 0, stream>>>(w0, b0, g0, h0);
  gemm_bt<true><<<dim3(16, 8), 256, 0, stream>>>(h0, w1T, h1t, b1, 2048, 1024, 1024);
  row_ln_k<true, true><<<2048, 256, 0, stream>>>(h1t, g1, nullptr, h1);
  btab_k<<<2048, 256, 0, stream>>>(h1, w2, b2, btab);
  // flash attention (flat LPT grid)
  attn_k<<<dim3(1024), 256, 0, stream>>>(qb, kbuf, vtb, btab, null_kv, nbias,
                                         k_scale, aout);
  // output projection + final LN
  gemm_bt<false><<<dim3(32, 8), 256, 0, stream>>>(aout, woT, opre, nullptr, 4096, 1024, 1024);
  row_ln_k<false, false><<<4096, 256, 0, stream>>>(opre, g_out, (float*)d_out, nullptr);
}

// Round 3
// 276.272 us; speedup vs baseline: 1.2163x; 1.2163x over previous
//
#include <hip/hip_runtime.h>

#define NSEQ 2048
#define DIMM 1024
#define NH   16
#define DH   64

using f32x4 = __attribute__((ext_vector_type(4))) float;
using s16x8 = __attribute__((ext_vector_type(8))) short;
using s16x4 = __attribute__((ext_vector_type(4))) short;

__device__ __forceinline__ short f2bf(float f) {
  union { float f; unsigned u; } a; a.f = f;
  unsigned r = (a.u + 0x7fffu + ((a.u >> 16) & 1u)) >> 16;
  return (short)(unsigned short)r;
}
__device__ __forceinline__ float bf2f(short s) {
  union { float f; unsigned u; } a; a.u = ((unsigned)(unsigned short)s) << 16;
  return a.f;
}

__device__ __forceinline__ void async_lds16(const void* g, void* l) {
  __builtin_amdgcn_global_load_lds(
      (const __attribute__((address_space(1))) void*)g,
      (__attribute__((address_space(3))) void*)l, 16, 0, 0);
}

__device__ __forceinline__ float wave_sum(float v) {
  v += __shfl_xor(v, 1);  v += __shfl_xor(v, 2);  v += __shfl_xor(v, 4);
  v += __shfl_xor(v, 8);  v += __shfl_xor(v, 16); v += __shfl_xor(v, 32);
  return v;
}

// ---------------- transpose + f32->bf16 convert: W (K x N) -> Wt (N x K) ----
__global__ __launch_bounds__(256) void transpose_w(const float* __restrict__ W,
                                                   short* __restrict__ Wt,
                                                   int K, int N) {
  __shared__ float tile[32][33];
  const int n0 = blockIdx.x * 32, k0 = blockIdx.y * 32;
  const int tx = threadIdx.x & 31, ty = threadIdx.x >> 5;
#pragma unroll
  for (int r = 0; r < 32; r += 8)
    tile[ty + r][tx] = W[(size_t)(k0 + ty + r) * N + n0 + tx];
  __syncthreads();
#pragma unroll
  for (int r = 0; r < 32; r += 8)
    Wt[(size_t)(n0 + ty + r) * K + k0 + tx] = f2bf(tile[tx][ty + r]);
}

// ---------------- row LayerNorm over 1024 cols (+optional SiLU) -------------
template <bool SILU, bool OUTBF>
__global__ __launch_bounds__(256) void row_ln_k(const float* __restrict__ in,
                                                const float* __restrict__ gamma,
                                                float* __restrict__ of,
                                                short* __restrict__ ob) {
  const int r = blockIdx.x, t = threadIdx.x;
  float4 x = *(const float4*)(in + (size_t)r * 1024 + t * 4);
  float v[4] = {x.x, x.y, x.z, x.w};
  float s  = v[0] + v[1] + v[2] + v[3];
  float ss = v[0]*v[0] + v[1]*v[1] + v[2]*v[2] + v[3]*v[3];
  s = wave_sum(s); ss = wave_sum(ss);
  __shared__ float rb[8];
  const int w = t >> 6, ln = t & 63;
  if (ln == 0) { rb[w] = s; rb[4 + w] = ss; }
  __syncthreads();
  s  = rb[0] + rb[1] + rb[2] + rb[3];
  ss = rb[4] + rb[5] + rb[6] + rb[7];
  const float mean = s * (1.f / 1024.f);
  const float inv  = rsqrtf(ss * (1.f / 1024.f) - mean * mean + 1e-5f);
  float4 gx = *(const float4*)(gamma + t * 4);
  float gg[4] = {gx.x, gx.y, gx.z, gx.w};
#pragma unroll
  for (int j = 0; j < 4; j++) {
    float y = (v[j] - mean) * inv * gg[j];
    if (SILU) y = y / (1.f + __expf(-y));
    v[j] = y;
  }
  if (OUTBF) {
    s16x4 o;
#pragma unroll
    for (int j = 0; j < 4; j++) o[j] = f2bf(v[j]);
    *(s16x4*)(ob + (size_t)r * 1024 + t * 4) = o;
  } else {
    *(float4*)(of + (size_t)r * 1024 + t * 4) = make_float4(v[0], v[1], v[2], v[3]);
  }
}

// ---------------- bias-MLP layer 0 ------------------------------------------
__global__ __launch_bounds__(256) void layer0_k(const float* __restrict__ w0,
                                                const float* __restrict__ b0,
                                                const float* __restrict__ g0,
                                                short* __restrict__ h0) {
  const int r = blockIdx.x, t = threadIdx.x;
  const float p = (float)r;
  float4 wv = *(const float4*)(w0 + t * 4);
  float4 bv = *(const float4*)(b0 + t * 4);
  float v[4] = {p * wv.x + bv.x, p * wv.y + bv.y, p * wv.z + bv.z, p * wv.w + bv.w};
  float s  = v[0] + v[1] + v[2] + v[3];
  float ss = v[0]*v[0] + v[1]*v[1] + v[2]*v[2] + v[3]*v[3];
  s = wave_sum(s); ss = wave_sum(ss);
  __shared__ float rb[8];
  const int w = t >> 6, ln = t & 63;
  if (ln == 0) { rb[w] = s; rb[4 + w] = ss; }
  __syncthreads();
  s  = rb[0] + rb[1] + rb[2] + rb[3];
  ss = rb[4] + rb[5] + rb[6] + rb[7];
  const float mean = s * (1.f / 1024.f);
  const float inv  = rsqrtf(ss * (1.f / 1024.f) - mean * mean + 1e-5f);
  float4 gx = *(const float4*)(g0 + t * 4);
  float gg[4] = {gx.x, gx.y, gx.z, gx.w};
  s16x4 o;
#pragma unroll
  for (int j = 0; j < 4; j++) {
    float y = (v[j] - mean) * inv * gg[j];
    y = y / (1.f + __expf(-y));
    o[j] = f2bf(y);
  }
  *(s16x4*)(h0 + (size_t)r * 1024 + t * 4) = o;
}

// ---------------- q post: l2norm per 64-group * q_scale -> bf16 -------------
__global__ __launch_bounds__(64) void post_q(const float* __restrict__ qt,
                                             const float* __restrict__ qs,
                                             short* __restrict__ qb) {
  const int g = blockIdx.x, d = threadIdx.x;
  const int r = g >> 4, h = g & 15;
  float v = qt[(size_t)r * 1152 + h * 64 + d];
  float ss = wave_sum(v * v);
  float n = fmaxf(sqrtf(ss), 1e-12f);
  qb[(size_t)g * 64 + d] = f2bf(v / n * qs[d]);
}

// ---------------- kv post ---------------------------------------------------
__global__ __launch_bounds__(128) void post_kv(const float* __restrict__ kvt,
                                               const float* __restrict__ ks,
                                               short* __restrict__ kb,
                                               short* __restrict__ vtb) {
  const int row = blockIdx.x, t = threadIdx.x;
  float v = kvt[(size_t)row * 1152 + 1024 + t];
  if (t < 64) {
    float ss = wave_sum(v * v);
    float n = fmaxf(sqrtf(ss), 1e-12f);
    kb[(size_t)row * 64 + t] = f2bf(v / n * ks[t]);
  } else {
    const int d = t - 64, b_ = row >> 11, i = row & 2047;
    vtb[((size_t)b_ * 64 + d) * NSEQ + i] = f2bf(v);
  }
}

// ---------------- btab: h1 @ w2 + b2 -> [16][2048] --------------------------
__global__ __launch_bounds__(256) void btab_k(const short* __restrict__ h1,
                                              const float* __restrict__ w2,
                                              const float* __restrict__ b2,
                                              float* __restrict__ btab) {
  const int r = blockIdx.x, t = threadIdx.x;
  const int n = t & 15, ck = t >> 4;
  float acc = 0.f;
  const short* hrow = h1 + (size_t)r * 1024 + ck * 64;
  const float* wcol = w2 + (size_t)(ck * 64) * 16 + n;
#pragma unroll 8
  for (int k = 0; k < 64; k++) acc += bf2f(hrow[k]) * wcol[k * 16];
  __shared__ float red[256];
  red[t] = acc;
  __syncthreads();
  if (t < 16) {
    float s = 0.f;
#pragma unroll
    for (int c = 0; c < 16; c++) s += red[c * 16 + t];
    btab[(size_t)t * NSEQ + r] = s + b2[t];
  }
}

// ---------------- per-head static max + pre-scaled bias table ---------------
// m_h = 8.25 + max(max_j btab[h][j], nbias[h]);  btab2 = (btab - m)*log2(e)
__global__ __launch_bounds__(256) void bmax_k(const float* __restrict__ btab,
                                              const float* __restrict__ nbias,
                                              float* __restrict__ btab2,
                                              float* __restrict__ mh) {
  const int h = blockIdx.x, t = threadIdx.x;
  const float* src = btab + (size_t)h * 2048;
  float mx = -3e38f;
  for (int j = t; j < 2048; j += 256) mx = fmaxf(mx, src[j]);
  mx = fmaxf(mx, __shfl_xor(mx, 1));  mx = fmaxf(mx, __shfl_xor(mx, 2));
  mx = fmaxf(mx, __shfl_xor(mx, 4));  mx = fmaxf(mx, __shfl_xor(mx, 8));
  mx = fmaxf(mx, __shfl_xor(mx, 16)); mx = fmaxf(mx, __shfl_xor(mx, 32));
  __shared__ float red[4];
  if ((t & 63) == 0) red[t >> 6] = mx;
  __syncthreads();
  float m = fmaxf(fmaxf(red[0], red[1]), fmaxf(red[2], red[3]));
  m = 8.25f + fmaxf(m, nbias[h]);
  if (t == 0) mh[h] = m;
  float* dst = btab2 + (size_t)h * 2048;
  for (int j = t; j < 2048; j += 256) dst[j] = (src[j] - m) * 1.44269504f;
}

// ---------------- GEMM: C = A * Bm^T (Bm is N x K bf16) ---------------------
template <bool ADD_BIAS>
__global__ __launch_bounds__(256, 2) void gemm_bt(const short* __restrict__ A,
                                                  const short* __restrict__ Bm,
                                                  float* __restrict__ C,
                                                  const float* __restrict__ bias,
                                                  int M, int N, int K) {
  __shared__ __align__(16) short Al[128 * 32];
  __shared__ __align__(16) short Bl[128 * 32];
  const int tid = threadIdx.x;
  const int lane = tid & 63;
  const int l15 = lane & 15, l4 = lane >> 4;
  const int wid = tid >> 6;
  const int wr = wid >> 1, wc = wid & 1;
  const int rowa0 = blockIdx.x * 128, rowb0 = blockIdx.y * 128;
  f32x4 acc[4][4];
#pragma unroll
  for (int m = 0; m < 4; m++)
#pragma unroll
    for (int n = 0; n < 4; n++) acc[m][n] = (f32x4){0.f, 0.f, 0.f, 0.f};

  const int sr = tid >> 2, sc = (tid & 3) * 8;
  const short* ga = A  + (size_t)(rowa0 + sr) * K + sc;
  const short* gb = Bm + (size_t)(rowb0 + sr) * K + sc;
  char* la = (char*)Al + wid * 1024;
  char* lb = (char*)Bl + wid * 1024;

  for (int k0 = 0; k0 < K; k0 += 32) {
    async_lds16(ga + k0,                  la);
    async_lds16(ga + (size_t)64 * K + k0, la + 4096);
    async_lds16(gb + k0,                  lb);
    async_lds16(gb + (size_t)64 * K + k0, lb + 4096);
    __syncthreads();
    s16x8 af[4], bfr[4];
#pragma unroll
    for (int m = 0; m < 4; m++)
      af[m] = *(const s16x8*)&Al[(wr * 64 + m * 16 + l15) * 32 + l4 * 8];
#pragma unroll
    for (int n = 0; n < 4; n++)
      bfr[n] = *(const s16x8*)&Bl[(wc * 64 + n * 16 + l15) * 32 + l4 * 8];
#pragma unroll
    for (int m = 0; m < 4; m++)
#pragma unroll
      for (int n = 0; n < 4; n++)
        acc[m][n] = __builtin_amdgcn_mfma_f32_16x16x32_bf16(af[m], bfr[n], acc[m][n], 0, 0, 0);
    __syncthreads();
  }
#pragma unroll
  for (int n = 0; n < 4; n++) {
    const int col = rowb0 + wc * 64 + n * 16 + l15;
    const float bv = ADD_BIAS ? bias[col] : 0.f;
#pragma unroll
    for (int m = 0; m < 4; m++) {
      const int row = rowa0 + wr * 64 + m * 16 + l4 * 4;
#pragma unroll
      for (int j = 0; j < 4; j++)
        C[(size_t)(row + j) * N + col] = acc[m][n][j] + bv;
    }
  }
}

// ---------------- flash attention v3: static-m, no cross-lane softmax -------
// grid 2048: split-K 2-way. Per block: 4 waves x 16 q-rows. Static per-head
// max => P = exp2(qk*8*log2e + btab2[rel]); row-sum rides in an MFMA
// ones-column; partials (O, lsum) just add across splits.
__global__ __launch_bounds__(256, 2) void attn_k(const short* __restrict__ q,
                                                 const short* __restrict__ kk,
                                                 const short* __restrict__ vt,
                                                 const float* __restrict__ btab2,
                                                 const float* __restrict__ mh,
                                                 const float* __restrict__ nkv,
                                                 const float* __restrict__ nbias,
                                                 const float* __restrict__ kscale,
                                                 float* __restrict__ opart0,
                                                 float* __restrict__ opart1,
                                                 float* __restrict__ lpart) {
  __shared__ __align__(16) float btl[2048];       // btab2 row h
  __shared__ __align__(16) short Pl[4 * 16 * 64]; // per-wave P, (slice+row)&7 swizzle
  __shared__ float nkn[64], nvv[64];

  const int tid = threadIdx.x;
  const int w = tid >> 6, lane = tid & 63;
  const int l15 = lane & 15, l4 = lane >> 4;
  const int bid = blockIdx.x;
  const int sp = bid & 1, rest = bid >> 1;
  const int b = rest & 1, h = (rest >> 1) & 15, qt = 31 - (rest >> 5);
  const int i0 = qt * 64;
  const int ntt = qt + 1, half = (ntt + 1) >> 1;
  const int t0 = sp ? half : 0, t1 = sp ? ntt : half;
  const int qrow0 = i0 + w * 16;

  // stage btab2[h] into LDS: per wave 2x 1KB
  {
    const float* src = btab2 + (size_t)h * 2048;
    async_lds16(src + w * 256 + lane * 4,        (char*)btl + w * 1024);
    async_lds16(src + 1024 + w * 256 + lane * 4, (char*)btl + 4096 + w * 1024);
  }
  if (w == 0) {
    float kx = nkv[lane];
    float ss = wave_sum(kx * kx);
    nkn[lane] = kx / fmaxf(sqrtf(ss), 1e-12f) * kscale[lane];
    nvv[lane] = nkv[64 + lane];
  }
  const short* qbase = q + (size_t)(b * NSEQ + qrow0) * DIMM + h * DH;
  s16x8 qf0 = *(const s16x8*)(qbase + (size_t)l15 * DIMM + l4 * 8);
  s16x8 qf1 = *(const s16x8*)(qbase + (size_t)l15 * DIMM + 32 + l4 * 8);
  const float m = mh[h];
  __syncthreads();   // btl + nkn/nvv ready (drains global_load_lds)

  // null-token contribution (split 0 only)
  float pnc = 0.f;
  if (sp == 0) {
    float sn = 0.f;
#pragma unroll
    for (int j = 0; j < 8; j++)
      sn += bf2f(qf0[j]) * nkn[l4 * 8 + j] + bf2f(qf1[j]) * nkn[32 + l4 * 8 + j];
    sn += __shfl_xor(sn, 16);
    sn += __shfl_xor(sn, 32);
    pnc = __builtin_amdgcn_exp2f(fmaf(sn, 11.5415603f, (nbias[h] - m) * 1.44269504f));
  }
  float pn[4];
#pragma unroll
  for (int jj = 0; jj < 4; jj++) pn[jj] = __shfl(pnc, l4 * 4 + jj);

  f32x4 o[4], o4;
#pragma unroll
  for (int dg = 0; dg < 4; dg++) {
    float nv = nvv[dg * 16 + l15];
#pragma unroll
    for (int jj = 0; jj < 4; jj++) o[dg][jj] = pn[jj] * nv;
  }
#pragma unroll
  for (int jj = 0; jj < 4; jj++) o4[jj] = pn[jj];

  // ones-column B fragment (col 0 = 1, rest 0) for the row-sum MFMA
  s16x8 vone;
#pragma unroll
  for (int j = 0; j < 8; j++) vone[j] = (l15 == 0) ? (short)0x3F80 : (short)0;

  const short* kbb = kk + (size_t)b * NSEQ * DH;
  const short* vbb = vt + (size_t)b * DH * NSEQ;
  char* pw = (char*)Pl + w * 2048;

  for (int t = t0; t < t1; ++t) {
    const int j0 = t * 64;
    s16x8 kf0[4], kf1[4], vf[2][4];
#pragma unroll
    for (int kb = 0; kb < 4; kb++) {
      const short* kp = kbb + (size_t)(j0 + kb * 16 + l15) * DH + l4 * 8;
      kf0[kb] = *(const s16x8*)kp;
      kf1[kb] = *(const s16x8*)(kp + 32);
    }
#pragma unroll
    for (int kc = 0; kc < 2; kc++)
#pragma unroll
      for (int dg = 0; dg < 4; dg++)
        vf[kc][dg] = *(const s16x8*)(vbb + (size_t)(dg * 16 + l15) * NSEQ +
                                     j0 + (kc * 4 + l4) * 8);
    f32x4 s[4];
#pragma unroll
    for (int kb = 0; kb < 4; kb++) {
      s[kb] = (f32x4){0.f, 0.f, 0.f, 0.f};
      s[kb] = __builtin_amdgcn_mfma_f32_16x16x32_bf16(qf0, kf0[kb], s[kb], 0, 0, 0);
      s[kb] = __builtin_amdgcn_mfma_f32_16x16x32_bf16(qf1, kf1[kb], s[kb], 0, 0, 0);
    }
    // P = exp2(qk*8*log2e + btab2[rel]), causal-masked; pack to swizzled LDS
#pragma unroll
    for (int kb = 0; kb < 4; kb++) {
      const int key = kb * 16 + l15;
      const int keyg = j0 + key;
#pragma unroll
      for (int jj = 0; jj < 4; jj++) {
        const int row = l4 * 4 + jj;
        const int rel = qrow0 + row - keyg;
        const float bb = btl[rel & 2047];
        const float sv = fmaf(s[kb][jj], 11.5415603f, bb);
        const float p = (rel >= 0) ? __builtin_amdgcn_exp2f(sv) : 0.f;
        *(short*)(pw + row * 128 + ((((key >> 3) + row) & 7) << 4) + ((key & 7) << 1)) =
            f2bf(p);
      }
    }
    // PV + ones-column (in-wave LDS ordering only)
#pragma unroll
    for (int kc = 0; kc < 2; kc++) {
      const int slice = kc * 4 + l4;
      s16x8 pf = *(const s16x8*)(pw + l15 * 128 + (((slice + l15) & 7) << 4));
#pragma unroll
      for (int dg = 0; dg < 4; dg++)
        o[dg] = __builtin_amdgcn_mfma_f32_16x16x32_bf16(pf, vf[kc][dg], o[dg], 0, 0, 0);
      o4 = __builtin_amdgcn_mfma_f32_16x16x32_bf16(pf, vone, o4, 0, 0, 0);
    }
  }

  // store partials
  const size_t rbase = (((size_t)b * 16 + h) * 2048 + i0 + w * 16);
  float* op = (sp ? opart1 : opart0) + rbase * 64;
#pragma unroll
  for (int dg = 0; dg < 4; dg++)
#pragma unroll
    for (int jj = 0; jj < 4; jj++)
      op[(size_t)(l4 * 4 + jj) * 64 + dg * 16 + l15] = o[dg][jj];
  if (l15 == 0) {
    float* lp = lpart + (size_t)sp * 65536 + rbase;
#pragma unroll
    for (int jj = 0; jj < 4; jj++) lp[l4 * 4 + jj] = o4[jj];
  }
}

// ---------------- combine splits: O = (O0+O1)/(l0+l1) -> bf16 aout ----------
__global__ __launch_bounds__(256) void combine_k(const float* __restrict__ opart0,
                                                 const float* __restrict__ opart1,
                                                 const float* __restrict__ lpart,
                                                 short* __restrict__ aout) {
  const int t = threadIdx.x;
  const int d = t & 63, rl = t >> 6;
  const int r = blockIdx.x * 4 + rl;
  const float o = opart0[(size_t)r * 64 + d] + opart1[(size_t)r * 64 + d];
  const float l = lpart[r] + lpart[65536 + r];
  const int b = (r >> 15) & 1, h = (r >> 11) & 15, i = r & 2047;
  aout[((size_t)(b * 2048 + i)) * 1024 + h * 64 + d] = f2bf(o / l);
}

// ---------------------------------------------------------------------------
extern "C" void kernel_launch(void* const* d_in, const int* in_sizes, int n_in,
                              void* d_out, int out_size, void* d_ws, size_t ws_size,
                              hipStream_t stream) {
  const float* x       = (const float*)d_in[0];
  const float* g_norm  = (const float*)d_in[2];
  const float* Wq      = (const float*)d_in[3];
  const float* Wkv     = (const float*)d_in[4];
  const float* q_scale = (const float*)d_in[5];
  const float* k_scale = (const float*)d_in[6];
  const float* null_kv = (const float*)d_in[7];
  const float* nbias   = (const float*)d_in[8];
  const float* w0      = (const float*)d_in[9];
  const float* b0      = (const float*)d_in[10];
  const float* g0      = (const float*)d_in[11];
  const float* w1      = (const float*)d_in[12];
  const float* b1      = (const float*)d_in[13];
  const float* g1      = (const float*)d_in[14];
  const float* w2      = (const float*)d_in[15];
  const float* b2      = (const float*)d_in[16];
  const float* Wout    = (const float*)d_in[17];
  const float* g_out   = (const float*)d_in[18];

  char* p = (char*)d_ws;
  auto alloc = [&](size_t bytes) {
    char* r = p; p += (bytes + 255) & ~(size_t)255; return r;
  };
  short* xn     = (short*)alloc((size_t)4096 * 1024 * 2);
  short* wqkvT  = (short*)alloc((size_t)1152 * 1024 * 2);
  short* w1T    = (short*)alloc((size_t)1024 * 1024 * 2);
  short* woT    = (short*)alloc((size_t)1024 * 1024 * 2);
  float* qkvtmp = (float*)alloc((size_t)4096 * 1152 * 4);   // 18.9 MB, multi-reused
  short* qb     = (short*)alloc((size_t)4096 * 1024 * 2);
  short* kbuf   = (short*)alloc((size_t)2 * NSEQ * DH * 2);
  short* vtb    = (short*)alloc((size_t)2 * DH * NSEQ * 2);
  short* h0     = (short*)alloc((size_t)2048 * 1024 * 2);
  short* h1     = (short*)alloc((size_t)2048 * 1024 * 2);
  float* btab   = (float*)alloc((size_t)16 * NSEQ * 4);
  float* btab2  = (float*)alloc((size_t)16 * NSEQ * 4);
  float* mh     = (float*)alloc(16 * 4);
  float* lpart  = (float*)alloc((size_t)2 * 65536 * 4);
  // time-sliced aliases:
  float* h1t    = qkvtmp;          // bias-MLP h1 pre-LN (dead before attn)
  float* opart0 = qkvtmp;          // attn split-0 partials (16.8 MB <= 18.9)
  float* opart1 = (float*)d_out;   // attn split-1 partials (d_out is 16.8 MB, rewritten at end)
  float* opre   = qkvtmp;          // out-proj result (written after combine)
  short* aout   = xn;              // attn bf16 output (xn dead after qkv gemm)

  transpose_w<<<dim3(32, 32), 256, 0, stream>>>(Wq,   wqkvT, 1024, 1024);
  transpose_w<<<dim3(4, 32),  256, 0, stream>>>(Wkv,  wqkvT + (size_t)1024 * 1024, 1024, 128);
  transpose_w<<<dim3(32, 32), 256, 0, stream>>>(w1,   w1T,  1024, 1024);
  transpose_w<<<dim3(32, 32), 256, 0, stream>>>(Wout, woT,  1024, 1024);
  row_ln_k<false, true><<<4096, 256, 0, stream>>>(x, g_norm, nullptr, xn);
  gemm_bt<false><<<dim3(32, 9), 256, 0, stream>>>(xn, wqkvT, qkvtmp, nullptr, 4096, 1152, 1024);
  post_q<<<65536, 64, 0, stream>>>(qkvtmp, q_scale, qb);
  post_kv<<<4096, 128, 0, stream>>>(qkvtmp, k_scale, kbuf, vtb);
  layer0_k<<<2048, 256, 0, stream>>>(w0, b0, g0, h0);
  gemm_bt<true><<<dim3(16, 8), 256, 0, stream>>>(h0, w1T, h1t, b1, 2048, 1024, 1024);
  row_ln_k<true, true><<<2048, 256, 0, stream>>>(h1t, g1, nullptr, h1);
  btab_k<<<2048, 256, 0, stream>>>(h1, w2, b2, btab);
  bmax_k<<<16, 256, 0, stream>>>(btab, nbias, btab2, mh);
  attn_k<<<dim3(2048), 256, 0, stream>>>(qb, kbuf, vtb, btab2, mh, null_kv, nbias,
                                         k_scale, opart0, opart1, lpart);
  combine_k<<<16384, 256, 0, stream>>>(opart0, opart1, lpart, aout);
  gemm_bt<false><<<dim3(32, 8), 256, 0, stream>>>(aout, woT, opre, nullptr, 4096, 1024, 1024);
  row_ln_k<false, false><<<4096, 256, 0, stream>>>(opre, g_out, (float*)d_out, nullptr);
}

// Round 5
// 161.716 us; speedup vs baseline: 2.0779x; 1.7084x over previous
//
#include <hip/hip_runtime.h>

#define NSEQ 2048
#define DIMM 1024
#define NH   16
#define DH   64

using f32x4 = __attribute__((ext_vector_type(4))) float;
using s16x8 = __attribute__((ext_vector_type(8))) short;
using s16x4 = __attribute__((ext_vector_type(4))) short;

__device__ __forceinline__ short f2bf(float f) {
  union { float f; unsigned u; } a; a.f = f;
  unsigned r = (a.u + 0x7fffu + ((a.u >> 16) & 1u)) >> 16;
  return (short)(unsigned short)r;
}
__device__ __forceinline__ float bf2f(short s) {
  union { float f; unsigned u; } a; a.u = ((unsigned)(unsigned short)s) << 16;
  return a.f;
}

__device__ __forceinline__ void async_lds16(const void* g, void* l) {
  __builtin_amdgcn_global_load_lds(
      (const __attribute__((address_space(1))) void*)g,
      (__attribute__((address_space(3))) void*)l, 16, 0, 0);
}

__device__ __forceinline__ float wave_sum(float v) {
  v += __shfl_xor(v, 1);  v += __shfl_xor(v, 2);  v += __shfl_xor(v, 4);
  v += __shfl_xor(v, 8);  v += __shfl_xor(v, 16); v += __shfl_xor(v, 32);
  return v;
}

// ---------------- all 4 weight transposes in one launch ---------------------
__global__ __launch_bounds__(256) void transpose_all(const float* __restrict__ Wq,
                                                     const float* __restrict__ Wkv,
                                                     const float* __restrict__ w1,
                                                     const float* __restrict__ Wout,
                                                     short* __restrict__ wqkvT,
                                                     short* __restrict__ w1T,
                                                     short* __restrict__ woT) {
  __shared__ float tile[32][33];
  const int bid = blockIdx.x;
  const float* W; short* Wt; int N, bx, by;
  if (bid < 1024)      { W = Wq;   Wt = wqkvT;                      N = 1024; bx = bid & 31;           by = bid >> 5; }
  else if (bid < 1152) { W = Wkv;  Wt = wqkvT + (size_t)1024 * 1024; N = 128; bx = (bid - 1024) & 3;   by = (bid - 1024) >> 2; }
  else if (bid < 2176) { W = w1;   Wt = w1T;                        N = 1024; bx = (bid - 1152) & 31;  by = (bid - 1152) >> 5; }
  else                 { W = Wout; Wt = woT;                        N = 1024; bx = (bid - 2176) & 31;  by = (bid - 2176) >> 5; }
  const int n0 = bx * 32, k0 = by * 32;
  const int tx = threadIdx.x & 31, ty = threadIdx.x >> 5;
#pragma unroll
  for (int r = 0; r < 32; r += 8)
    tile[ty + r][tx] = W[(size_t)(k0 + ty + r) * N + n0 + tx];
  __syncthreads();
#pragma unroll
  for (int r = 0; r < 32; r += 8)
    Wt[(size_t)(n0 + ty + r) * 1024 + k0 + tx] = f2bf(tile[tx][ty + r]);
}

// ---------------- row LayerNorm over 1024 cols (+optional SiLU) -------------
template <bool SILU, bool OUTBF>
__global__ __launch_bounds__(256) void row_ln_k(const float* __restrict__ in,
                                                const float* __restrict__ gamma,
                                                float* __restrict__ of,
                                                short* __restrict__ ob) {
  const int r = blockIdx.x, t = threadIdx.x;
  float4 x = *(const float4*)(in + (size_t)r * 1024 + t * 4);
  float v[4] = {x.x, x.y, x.z, x.w};
  float s  = v[0] + v[1] + v[2] + v[3];
  float ss = v[0]*v[0] + v[1]*v[1] + v[2]*v[2] + v[3]*v[3];
  s = wave_sum(s); ss = wave_sum(ss);
  __shared__ float rb[8];
  const int w = t >> 6, ln = t & 63;
  if (ln == 0) { rb[w] = s; rb[4 + w] = ss; }
  __syncthreads();
  s  = rb[0] + rb[1] + rb[2] + rb[3];
  ss = rb[4] + rb[5] + rb[6] + rb[7];
  const float mean = s * (1.f / 1024.f);
  const float inv  = rsqrtf(ss * (1.f / 1024.f) - mean * mean + 1e-5f);
  float4 gx = *(const float4*)(gamma + t * 4);
  float gg[4] = {gx.x, gx.y, gx.z, gx.w};
#pragma unroll
  for (int j = 0; j < 4; j++) {
    float y = (v[j] - mean) * inv * gg[j];
    if (SILU) y = y / (1.f + __expf(-y));
    v[j] = y;
  }
  if (OUTBF) {
    s16x4 o;
#pragma unroll
    for (int j = 0; j < 4; j++) o[j] = f2bf(v[j]);
    *(s16x4*)(ob + (size_t)r * 1024 + t * 4) = o;
  } else {
    *(float4*)(of + (size_t)r * 1024 + t * 4) = make_float4(v[0], v[1], v[2], v[3]);
  }
}

// ---------------- bias-MLP layer 0 ------------------------------------------
__global__ __launch_bounds__(256) void layer0_k(const float* __restrict__ w0,
                                                const float* __restrict__ b0,
                                                const float* __restrict__ g0,
                                                short* __restrict__ h0) {
  const int r = blockIdx.x, t = threadIdx.x;
  const float p = (float)r;
  float4 wv = *(const float4*)(w0 + t * 4);
  float4 bv = *(const float4*)(b0 + t * 4);
  float v[4] = {p * wv.x + bv.x, p * wv.y + bv.y, p * wv.z + bv.z, p * wv.w + bv.w};
  float s  = v[0] + v[1] + v[2] + v[3];
  float ss = v[0]*v[0] + v[1]*v[1] + v[2]*v[2] + v[3]*v[3];
  s = wave_sum(s); ss = wave_sum(ss);
  __shared__ float rb[8];
  const int w = t >> 6, ln = t & 63;
  if (ln == 0) { rb[w] = s; rb[4 + w] = ss; }
  __syncthreads();
  s  = rb[0] + rb[1] + rb[2] + rb[3];
  ss = rb[4] + rb[5] + rb[6] + rb[7];
  const float mean = s * (1.f / 1024.f);
  const float inv  = rsqrtf(ss * (1.f / 1024.f) - mean * mean + 1e-5f);
  float4 gx = *(const float4*)(g0 + t * 4);
  float gg[4] = {gx.x, gx.y, gx.z, gx.w};
  s16x4 o;
#pragma unroll
  for (int j = 0; j < 4; j++) {
    float y = (v[j] - mean) * inv * gg[j];
    y = y / (1.f + __expf(-y));
    o[j] = f2bf(y);
  }
  *(s16x4*)(h0 + (size_t)r * 1024 + t * 4) = o;
}

// ---------------- btab: h1 @ w2 + b2 -> [16][2048] --------------------------
__global__ __launch_bounds__(256) void btab_k(const short* __restrict__ h1,
                                              const float* __restrict__ w2,
                                              const float* __restrict__ b2,
                                              float* __restrict__ btab) {
  const int r = blockIdx.x, t = threadIdx.x;
  const int n = t & 15, ck = t >> 4;
  float acc = 0.f;
  const short* hrow = h1 + (size_t)r * 1024 + ck * 64;
  const float* wcol = w2 + (size_t)(ck * 64) * 16 + n;
#pragma unroll 8
  for (int k = 0; k < 64; k++) acc += bf2f(hrow[k]) * wcol[k * 16];
  __shared__ float red[256];
  red[t] = acc;
  __syncthreads();
  if (t < 16) {
    float s = 0.f;
#pragma unroll
    for (int c = 0; c < 16; c++) s += red[c * 16 + t];
    btab[(size_t)t * NSEQ + r] = s + b2[t];
  }
}

// ---------------- per-head static max + pre-scaled bias table ---------------
__global__ __launch_bounds__(256) void bmax_k(const float* __restrict__ btab,
                                              const float* __restrict__ nbias,
                                              float* __restrict__ btab2,
                                              float* __restrict__ mh) {
  const int h = blockIdx.x, t = threadIdx.x;
  const float* src = btab + (size_t)h * 2048;
  float mx = -3e38f;
  for (int j = t; j < 2048; j += 256) mx = fmaxf(mx, src[j]);
  mx = fmaxf(mx, __shfl_xor(mx, 1));  mx = fmaxf(mx, __shfl_xor(mx, 2));
  mx = fmaxf(mx, __shfl_xor(mx, 4));  mx = fmaxf(mx, __shfl_xor(mx, 8));
  mx = fmaxf(mx, __shfl_xor(mx, 16)); mx = fmaxf(mx, __shfl_xor(mx, 32));
  __shared__ float red[4];
  if ((t & 63) == 0) red[t >> 6] = mx;
  __syncthreads();
  float m = fmaxf(fmaxf(red[0], red[1]), fmaxf(red[2], red[3]));
  m = 8.25f + fmaxf(m, nbias[h]);
  if (t == 0) mh[h] = m;
  float* dst = btab2 + (size_t)h * 2048;
  for (int j = t; j < 2048; j += 256) dst[j] = (src[j] - m) * 1.44269504f;
}

// ---------------- GEMM: C = A * Bm^T, double-buffered; EPI=1 fuses qkv post -
template <int EPI, bool ADD_BIAS>
__global__ __launch_bounds__(256, 2) void gemm_bt(const short* __restrict__ A,
                                                  const short* __restrict__ Bm,
                                                  float* __restrict__ C,
                                                  const float* __restrict__ bias,
                                                  const float* __restrict__ qs,
                                                  const float* __restrict__ ks,
                                                  short* __restrict__ qb,
                                                  short* __restrict__ kb,
                                                  short* __restrict__ vtb,
                                                  int M, int N, int K) {
  __shared__ __align__(16) short Al[2][128 * 32];
  __shared__ __align__(16) short Bl[2][128 * 32];
  const int tid = threadIdx.x;
  const int lane = tid & 63;
  const int l15 = lane & 15, l4 = lane >> 4;
  const int wid = tid >> 6;
  const int wr = wid >> 1, wc = wid & 1;
  const int rowa0 = blockIdx.x * 128, rowb0 = blockIdx.y * 128;
  f32x4 acc[4][4];
#pragma unroll
  for (int m = 0; m < 4; m++)
#pragma unroll
    for (int n = 0; n < 4; n++) acc[m][n] = (f32x4){0.f, 0.f, 0.f, 0.f};

  const int sr = tid >> 2, sc = (tid & 3) * 8;
  const short* ga = A  + (size_t)(rowa0 + sr) * K + sc;
  const short* gb = Bm + (size_t)(rowb0 + sr) * K + sc;

  auto stage = [&](int buf, int k0) {
    char* la = (char*)Al[buf] + wid * 1024;
    char* lb = (char*)Bl[buf] + wid * 1024;
    async_lds16(ga + k0,                  la);
    async_lds16(ga + (size_t)64 * K + k0, la + 4096);
    async_lds16(gb + k0,                  lb);
    async_lds16(gb + (size_t)64 * K + k0, lb + 4096);
  };

  stage(0, 0);
  int cur = 0;
  for (int k0 = 0; k0 < K; k0 += 32) {
    __syncthreads();                       // staged data for `cur` ready
    if (k0 + 32 < K) stage(cur ^ 1, k0 + 32);   // prefetch overlaps compute
    s16x8 af[4], bfr[4];
#pragma unroll
    for (int m = 0; m < 4; m++)
      af[m] = *(const s16x8*)&Al[cur][(wr * 64 + m * 16 + l15) * 32 + l4 * 8];
#pragma unroll
    for (int n = 0; n < 4; n++)
      bfr[n] = *(const s16x8*)&Bl[cur][(wc * 64 + n * 16 + l15) * 32 + l4 * 8];
#pragma unroll
    for (int m = 0; m < 4; m++)
#pragma unroll
      for (int n = 0; n < 4; n++)
        acc[m][n] = __builtin_amdgcn_mfma_f32_16x16x32_bf16(af[m], bfr[n], acc[m][n], 0, 0, 0);
    cur ^= 1;
  }

  if (EPI == 0) {
#pragma unroll
    for (int n = 0; n < 4; n++) {
      const int col = rowb0 + wc * 64 + n * 16 + l15;
      const float bv = ADD_BIAS ? bias[col] : 0.f;
#pragma unroll
      for (int m = 0; m < 4; m++) {
        const int row = rowa0 + wr * 64 + m * 16 + l4 * 4;
#pragma unroll
        for (int j = 0; j < 4; j++)
          C[(size_t)(row + j) * N + col] = acc[m][n][j] + bv;
      }
    }
  } else {
    const int colbase = rowb0 + wc * 64;
    const int rowg0 = rowa0 + wr * 64;
    if (colbase < 1024 || wc == 0) {
      // q head (cols<1024) or k (cols 1024..1087): row-wise l2norm over 64 cols
      const bool isq = (colbase < 1024);
      const float* scp = isq ? qs : ks;
#pragma unroll
      for (int m = 0; m < 4; m++) {
        float inv[4];
#pragma unroll
        for (int jj = 0; jj < 4; jj++) {
          float ssq = 0.f;
#pragma unroll
          for (int n = 0; n < 4; n++) ssq += acc[m][n][jj] * acc[m][n][jj];
          ssq += __shfl_xor(ssq, 1); ssq += __shfl_xor(ssq, 2);
          ssq += __shfl_xor(ssq, 4); ssq += __shfl_xor(ssq, 8);
          inv[jj] = 1.f / fmaxf(sqrtf(ssq), 1e-12f);
        }
#pragma unroll
        for (int n = 0; n < 4; n++) {
          const int d = n * 16 + l15;
          const float sc2 = scp[d];
#pragma unroll
          for (int jj = 0; jj < 4; jj++) {
            const int row = rowg0 + m * 16 + l4 * 4 + jj;
            const short v = f2bf(acc[m][n][jj] * inv[jj] * sc2);
            if (isq) qb[(size_t)row * 1024 + colbase + d] = v;
            else     kb[(size_t)row * 64 + d] = v;
          }
        }
      }
    } else {
      // v (cols 1088..1151): transposed bf16 store
#pragma unroll
      for (int m = 0; m < 4; m++)
#pragma unroll
        for (int n = 0; n < 4; n++) {
          const int d = n * 16 + l15;
          const int row = rowg0 + m * 16 + l4 * 4;
          const int bb = row >> 11, ii = row & 2047;
          s16x4 o;
#pragma unroll
          for (int jj = 0; jj < 4; jj++) o[jj] = f2bf(acc[m][n][jj]);
          *(s16x4*)(vtb + ((size_t)(bb * 64 + d)) * 2048 + ii) = o;
        }
    }
  }
}

// ---------------- flash attention v4: LDS K/V double-buffer, static-m -------
// grid 1024 LPT, no split-K. 4 waves x 16 q-rows. K/V staged per block via
// global_load_lds (pre-swizzled source), prefetched one tile ahead; one
// barrier per tile drains the prefetch. Row-sum via ALL-ONES MFMA B-operand
// (every output column = rowsum -> every lane holds the denominator; fixes
// round-4's col-0-only bug).
__global__ __launch_bounds__(256, 2) void attn_k(const short* __restrict__ q,
                                                 const short* __restrict__ kk,
                                                 const short* __restrict__ vt,
                                                 const float* __restrict__ btab2,
                                                 const float* __restrict__ mh,
                                                 const float* __restrict__ nkv,
                                                 const float* __restrict__ nbias,
                                                 const float* __restrict__ kscale,
                                                 short* __restrict__ aout) {
  __shared__ __align__(16) short Kl[2][64 * 64];   // 16 KB, swizzled [key][d]
  __shared__ __align__(16) short Vl[2][64 * 64];   // 16 KB, swizzled [d][key]
  __shared__ __align__(16) short Pl[4 * 16 * 64];  // 8 KB per-wave P
  __shared__ __align__(16) float btl[2048];        // 8 KB bias row
  __shared__ float nkn[64], nvv[64];

  const int tid = threadIdx.x;
  const int w = tid >> 6, lane = tid & 63;
  const int l15 = lane & 15, l4 = lane >> 4;
  const int bid = blockIdx.x;
  const int b = bid & 1, h = (bid >> 1) & 15, qt = 31 - (bid >> 5);
  const int i0 = qt * 64;
  const int nt = qt + 1;
  const int qrow0 = i0 + w * 16;

  // stage btab2 row h
  const float* bsrc = btab2 + (size_t)h * 2048;
  async_lds16(bsrc + w * 256 + lane * 4,        (char*)btl + w * 1024);
  async_lds16(bsrc + 1024 + w * 256 + lane * 4, (char*)btl + 4096 + w * 1024);

  const int sr = tid >> 3;                    // 0..31
  const int sb = (tid & 7) ^ (sr & 7);        // pre-swizzled source block
  const short* gk = kk + ((size_t)(b * NSEQ) + sr) * DH + sb * 8;
  const short* gv = vt + ((size_t)b * DH + sr) * NSEQ + sb * 8;

  // stage K/V tile 0 into buf 0
  async_lds16(gk,             (char*)Kl[0] + w * 1024);
  async_lds16(gk + 32 * DH,   (char*)Kl[0] + 4096 + w * 1024);
  async_lds16(gv,             (char*)Vl[0] + w * 1024);
  async_lds16(gv + 32 * NSEQ, (char*)Vl[0] + 4096 + w * 1024);

  if (w == 0) {
    float kx = nkv[lane];
    float ssn = wave_sum(kx * kx);
    nkn[lane] = kx / fmaxf(sqrtf(ssn), 1e-12f) * kscale[lane];
    nvv[lane] = nkv[64 + lane];
  }
  const short* qbase = q + (size_t)(b * NSEQ + qrow0) * DIMM + h * DH;
  s16x8 qf0 = *(const s16x8*)(qbase + (size_t)l15 * DIMM + l4 * 8);
  s16x8 qf1 = *(const s16x8*)(qbase + (size_t)l15 * DIMM + 32 + l4 * 8);
  const float m = mh[h];
  __syncthreads();   // drains tile-0 DMA + btl; nkn/nvv visible

  // null-token init
  float sn = 0.f;
#pragma unroll
  for (int j = 0; j < 8; j++)
    sn += bf2f(qf0[j]) * nkn[l4 * 8 + j] + bf2f(qf1[j]) * nkn[32 + l4 * 8 + j];
  sn += __shfl_xor(sn, 16);
  sn += __shfl_xor(sn, 32);
  const float pnc = __builtin_amdgcn_exp2f(fmaf(sn, 11.5415603f,
                                                (nbias[h] - m) * 1.44269504f));
  float pn[4];
#pragma unroll
  for (int jj = 0; jj < 4; jj++) pn[jj] = __shfl(pnc, l4 * 4 + jj);

  f32x4 o[4], o4;
#pragma unroll
  for (int dg = 0; dg < 4; dg++) {
    float nv = nvv[dg * 16 + l15];
#pragma unroll
    for (int jj = 0; jj < 4; jj++) o[dg][jj] = pn[jj] * nv;
  }
#pragma unroll
  for (int jj = 0; jj < 4; jj++) o4[jj] = pn[jj];

  // ALL-ONES B fragment: every output column accumulates the row-sum
  s16x8 vone;
#pragma unroll
  for (int j = 0; j < 8; j++) vone[j] = (short)0x3F80;

  char* pw = (char*)Pl + w * 2048;
  int cur = 0;

  for (int t = 0; t < nt; ++t) {
    // prefetch next K/V tile into the other buffer (overlaps compute below)
    if (t + 1 < nt) {
      const int jn = (t + 1) * 64;
      async_lds16(gk + (size_t)jn * DH,        (char*)Kl[cur ^ 1] + w * 1024);
      async_lds16(gk + (size_t)(jn + 32) * DH, (char*)Kl[cur ^ 1] + 4096 + w * 1024);
      async_lds16(gv + jn,                     (char*)Vl[cur ^ 1] + w * 1024);
      async_lds16(gv + 32 * NSEQ + jn,         (char*)Vl[cur ^ 1] + 4096 + w * 1024);
    }
    const int j0 = t * 64;
    // QK^T from LDS
    f32x4 s[4];
#pragma unroll
    for (int kb2 = 0; kb2 < 4; kb2++) s[kb2] = (f32x4){0.f, 0.f, 0.f, 0.f};
#pragma unroll
    for (int c = 0; c < 2; c++) {
#pragma unroll
      for (int kb2 = 0; kb2 < 4; kb2++) {
        const int key = kb2 * 16 + l15;
        s16x8 kf = *(const s16x8*)((const char*)Kl[cur] + key * 128 +
                                   ((((c << 2) + l4) ^ (key & 7)) << 4));
        s[kb2] = __builtin_amdgcn_mfma_f32_16x16x32_bf16(c == 0 ? qf0 : qf1, kf, s[kb2], 0, 0, 0);
      }
    }
    // P = exp2(qk*8*log2e + btab2[rel]); causal mask; pack to swizzled LDS
#pragma unroll
    for (int kb2 = 0; kb2 < 4; kb2++) {
      const int key = kb2 * 16 + l15;
      const int keyg = j0 + key;
#pragma unroll
      for (int jj = 0; jj < 4; jj++) {
        const int row = l4 * 4 + jj;
        const int rel = qrow0 + row - keyg;
        const float bb = btl[rel & 2047];
        const float sv = fmaf(s[kb2][jj], 11.5415603f, bb);
        const float pp = (rel >= 0) ? __builtin_amdgcn_exp2f(sv) : 0.f;
        *(short*)(pw + row * 128 + ((((key >> 3) + row) & 7) << 4) + ((key & 7) << 1)) =
            f2bf(pp);
      }
    }
    // PV + all-ones row-sum
#pragma unroll
    for (int kc = 0; kc < 2; kc++) {
      const int slice = kc * 4 + l4;
      s16x8 pf = *(const s16x8*)(pw + l15 * 128 + (((slice + l15) & 7) << 4));
#pragma unroll
      for (int dg = 0; dg < 4; dg++) {
        const int d = dg * 16 + l15;
        s16x8 vf = *(const s16x8*)((const char*)Vl[cur] + d * 128 +
                                   ((slice ^ (d & 7)) << 4));
        o[dg] = __builtin_amdgcn_mfma_f32_16x16x32_bf16(pf, vf, o[dg], 0, 0, 0);
      }
      o4 = __builtin_amdgcn_mfma_f32_16x16x32_bf16(pf, vone, o4, 0, 0, 0);
    }
    __syncthreads();    // all waves done with `cur`; prefetch into cur^1 drained
    cur ^= 1;
  }

  // epilogue: reuse Kl (dead) as per-wave f32 staging for coalesced store
  float* ob = (float*)Kl + w * 1024;
#pragma unroll
  for (int dg = 0; dg < 4; dg++)
#pragma unroll
    for (int jj = 0; jj < 4; jj++)
      ob[(l4 * 4 + jj) * 64 + dg * 16 + l15] = o[dg][jj] / o4[jj];
  const int orow = lane >> 2, oc = (lane & 3) * 16;
  const float* srcp = ob + orow * 64 + oc;
  s16x8 r0, r1;
#pragma unroll
  for (int j = 0; j < 8; j++) { r0[j] = f2bf(srcp[j]); r1[j] = f2bf(srcp[8 + j]); }
  short* gout = aout + (size_t)(b * NSEQ + i0 + w * 16 + orow) * DIMM + h * DH + oc;
  *(s16x8*)gout = r0;
  *(s16x8*)(gout + 8) = r1;
}

// ---------------------------------------------------------------------------
extern "C" void kernel_launch(void* const* d_in, const int* in_sizes, int n_in,
                              void* d_out, int out_size, void* d_ws, size_t ws_size,
                              hipStream_t stream) {
  const float* x       = (const float*)d_in[0];
  const float* g_norm  = (const float*)d_in[2];
  const float* Wq      = (const float*)d_in[3];
  const float* Wkv     = (const float*)d_in[4];
  const float* q_scale = (const float*)d_in[5];
  const float* k_scale = (const float*)d_in[6];
  const float* null_kv = (const float*)d_in[7];
  const float* nbias   = (const float*)d_in[8];
  const float* w0      = (const float*)d_in[9];
  const float* b0      = (const float*)d_in[10];
  const float* g0      = (const float*)d_in[11];
  const float* w1      = (const float*)d_in[12];
  const float* b1      = (const float*)d_in[13];
  const float* g1      = (const float*)d_in[14];
  const float* w2      = (const float*)d_in[15];
  const float* b2      = (const float*)d_in[16];
  const float* Wout    = (const float*)d_in[17];
  const float* g_out   = (const float*)d_in[18];

  char* p = (char*)d_ws;
  auto alloc = [&](size_t bytes) {
    char* r = p; p += (bytes + 255) & ~(size_t)255; return r;
  };
  short* xn     = (short*)alloc((size_t)4096 * 1024 * 2);
  short* wqkvT  = (short*)alloc((size_t)1152 * 1024 * 2);
  short* w1T    = (short*)alloc((size_t)1024 * 1024 * 2);
  short* woT    = (short*)alloc((size_t)1024 * 1024 * 2);
  short* qb     = (short*)alloc((size_t)4096 * 1024 * 2);
  short* kbuf   = (short*)alloc((size_t)2 * NSEQ * DH * 2);
  short* vtb    = (short*)alloc((size_t)2 * DH * NSEQ * 2);
  short* h0     = (short*)alloc((size_t)2048 * 1024 * 2);
  short* h1     = (short*)alloc((size_t)2048 * 1024 * 2);
  float* btab   = (float*)alloc((size_t)16 * NSEQ * 4);
  float* btab2  = (float*)alloc((size_t)16 * NSEQ * 4);
  float* mh     = (float*)alloc(16 * 4);
  float* opre   = (float*)alloc((size_t)4096 * 1024 * 4);  // 16.8 MB
  // time-sliced aliases:
  float* h1t  = opre;            // bias-MLP h1 pre-LN (dead before out-proj)
  short* aout = xn;              // attn output (xn dead after qkv gemm)

  transpose_all<<<3200, 256, 0, stream>>>(Wq, Wkv, w1, Wout, wqkvT, w1T, woT);
  row_ln_k<false, true><<<4096, 256, 0, stream>>>(x, g_norm, nullptr, xn);
  // fused qkv projection + l2norm/scale/transpose epilogue
  gemm_bt<1, false><<<dim3(32, 9), 256, 0, stream>>>(xn, wqkvT, nullptr, nullptr,
                                                     q_scale, k_scale, qb, kbuf, vtb,
                                                     4096, 1152, 1024);
  // rel-pos bias MLP
  layer0_k<<<2048, 256, 0, stream>>>(w0, b0, g0, h0);
  gemm_bt<0, true><<<dim3(16, 8), 256, 0, stream>>>(h0, w1T, h1t, b1,
                                                    nullptr, nullptr, nullptr, nullptr, nullptr,
                                                    2048, 1024, 1024);
  row_ln_k<true, true><<<2048, 256, 0, stream>>>(h1t, g1, nullptr, h1);
  btab_k<<<2048, 256, 0, stream>>>(h1, w2, b2, btab);
  bmax_k<<<16, 256, 0, stream>>>(btab, nbias, btab2, mh);
  // flash attention (no split, LPT)
  attn_k<<<dim3(1024), 256, 0, stream>>>(qb, kbuf, vtb, btab2, mh, null_kv, nbias,
                                         k_scale, aout);
  // output projection + final LN
  gemm_bt<0, false><<<dim3(32, 8), 256, 0, stream>>>(aout, woT, opre,
                                                     nullptr, nullptr, nullptr, nullptr, nullptr, nullptr,
                                                     4096, 1024, 1024);
  row_ln_k<false, false><<<4096, 256, 0, stream>>>(opre, g_out, (float*)d_out, nullptr);
}

// Round 6
// 140.492 us; speedup vs baseline: 2.3918x; 1.1511x over previous
//
#include <hip/hip_runtime.h>

#define NSEQ 2048
#define DIMM 1024
#define NH   16
#define DH   64

using f32x4 = __attribute__((ext_vector_type(4))) float;
using s16x8 = __attribute__((ext_vector_type(8))) short;
using s16x4 = __attribute__((ext_vector_type(4))) short;

__device__ __forceinline__ short f2bf(float f) {
  union { float f; unsigned u; } a; a.f = f;
  unsigned r = (a.u + 0x7fffu + ((a.u >> 16) & 1u)) >> 16;
  return (short)(unsigned short)r;
}
__device__ __forceinline__ float bf2f(short s) {
  union { float f; unsigned u; } a; a.u = ((unsigned)(unsigned short)s) << 16;
  return a.f;
}
__device__ __forceinline__ unsigned cvtpk_bf16(float lo, float hi) {
  unsigned r;
  asm("v_cvt_pk_bf16_f32 %0, %1, %2" : "=v"(r) : "v"(lo), "v"(hi));
  return r;
}

__device__ __forceinline__ void async_lds16(const void* g, void* l) {
  __builtin_amdgcn_global_load_lds(
      (const __attribute__((address_space(1))) void*)g,
      (__attribute__((address_space(3))) void*)l, 16, 0, 0);
}

__device__ __forceinline__ float wave_sum(float v) {
  v += __shfl_xor(v, 1);  v += __shfl_xor(v, 2);  v += __shfl_xor(v, 4);
  v += __shfl_xor(v, 8);  v += __shfl_xor(v, 16); v += __shfl_xor(v, 32);
  return v;
}

// ---------------- prep: 4 weight transposes + LN(x) + bias-MLP layer0 -------
// bid < 3200: transpose jobs; < 7296: row-LN of x -> xn bf16; else layer0.
__global__ __launch_bounds__(256) void prep_k(const float* __restrict__ x,
                                              const float* __restrict__ g_norm,
                                              const float* __restrict__ w0,
                                              const float* __restrict__ b0,
                                              const float* __restrict__ g0,
                                              const float* __restrict__ Wq,
                                              const float* __restrict__ Wkv,
                                              const float* __restrict__ w1,
                                              const float* __restrict__ Wout,
                                              short* __restrict__ xn,
                                              short* __restrict__ h0,
                                              short* __restrict__ wqkvT,
                                              short* __restrict__ w1T,
                                              short* __restrict__ woT) {
  __shared__ float tile[32][33];
  __shared__ float rb[8];
  const int bid = blockIdx.x, t = threadIdx.x;
  if (bid < 3200) {
    const float* W; short* Wt; int N, bx, by;
    if (bid < 1024)      { W = Wq;   Wt = wqkvT;                       N = 1024; bx = bid & 31;          by = bid >> 5; }
    else if (bid < 1152) { W = Wkv;  Wt = wqkvT + (size_t)1024 * 1024; N = 128;  bx = (bid - 1024) & 3;  by = (bid - 1024) >> 2; }
    else if (bid < 2176) { W = w1;   Wt = w1T;                         N = 1024; bx = (bid - 1152) & 31; by = (bid - 1152) >> 5; }
    else                 { W = Wout; Wt = woT;                         N = 1024; bx = (bid - 2176) & 31; by = (bid - 2176) >> 5; }
    const int n0 = bx * 32, k0 = by * 32;
    const int tx = t & 31, ty = t >> 5;
#pragma unroll
    for (int r = 0; r < 32; r += 8)
      tile[ty + r][tx] = W[(size_t)(k0 + ty + r) * N + n0 + tx];
    __syncthreads();
#pragma unroll
    for (int r = 0; r < 32; r += 8)
      Wt[(size_t)(n0 + ty + r) * 1024 + k0 + tx] = f2bf(tile[tx][ty + r]);
    return;
  }
  const bool isln = (bid < 7296);
  const int r = isln ? (bid - 3200) : (bid - 7296);
  float v[4];
  if (isln) {
    float4 xv = *(const float4*)(x + (size_t)r * 1024 + t * 4);
    v[0] = xv.x; v[1] = xv.y; v[2] = xv.z; v[3] = xv.w;
  } else {
    const float p = (float)r;
    float4 wv = *(const float4*)(w0 + t * 4);
    float4 bv = *(const float4*)(b0 + t * 4);
    v[0] = p * wv.x + bv.x; v[1] = p * wv.y + bv.y;
    v[2] = p * wv.z + bv.z; v[3] = p * wv.w + bv.w;
  }
  float s  = v[0] + v[1] + v[2] + v[3];
  float ss = v[0]*v[0] + v[1]*v[1] + v[2]*v[2] + v[3]*v[3];
  s = wave_sum(s); ss = wave_sum(ss);
  const int w = t >> 6, ln = t & 63;
  if (ln == 0) { rb[w] = s; rb[4 + w] = ss; }
  __syncthreads();
  s  = rb[0] + rb[1] + rb[2] + rb[3];
  ss = rb[4] + rb[5] + rb[6] + rb[7];
  const float mean = s * (1.f / 1024.f);
  const float inv  = rsqrtf(ss * (1.f / 1024.f) - mean * mean + 1e-5f);
  const float* gp = isln ? g_norm : g0;
  float4 gx = *(const float4*)(gp + t * 4);
  float gg[4] = {gx.x, gx.y, gx.z, gx.w};
  s16x4 o;
#pragma unroll
  for (int j = 0; j < 4; j++) {
    float y = (v[j] - mean) * inv * gg[j];
    if (!isln) y = y / (1.f + __expf(-y));
    o[j] = f2bf(y);
  }
  short* dst = isln ? xn : h0;
  *(s16x4*)(dst + (size_t)r * 1024 + t * 4) = o;
}

// ---------------- btab: LN+silu of h1t rows fused with @ w2 + b2 ------------
__global__ __launch_bounds__(256) void btab_k(const float* __restrict__ h1t,
                                              const float* __restrict__ g1,
                                              const float* __restrict__ w2,
                                              const float* __restrict__ b2,
                                              float* __restrict__ btab) {
  __shared__ float hs[1024];
  __shared__ float rb[8];
  __shared__ float red[256];
  const int r = blockIdx.x, t = threadIdx.x;
  float4 xv = *(const float4*)(h1t + (size_t)r * 1024 + t * 4);
  float v[4] = {xv.x, xv.y, xv.z, xv.w};
  float s  = v[0] + v[1] + v[2] + v[3];
  float ss = v[0]*v[0] + v[1]*v[1] + v[2]*v[2] + v[3]*v[3];
  s = wave_sum(s); ss = wave_sum(ss);
  const int w = t >> 6, ln = t & 63;
  if (ln == 0) { rb[w] = s; rb[4 + w] = ss; }
  __syncthreads();
  s  = rb[0] + rb[1] + rb[2] + rb[3];
  ss = rb[4] + rb[5] + rb[6] + rb[7];
  const float mean = s * (1.f / 1024.f);
  const float inv  = rsqrtf(ss * (1.f / 1024.f) - mean * mean + 1e-5f);
  float4 gx = *(const float4*)(g1 + t * 4);
  float gg[4] = {gx.x, gx.y, gx.z, gx.w};
#pragma unroll
  for (int j = 0; j < 4; j++) {
    float y = (v[j] - mean) * inv * gg[j];
    hs[t * 4 + j] = y / (1.f + __expf(-y));
  }
  __syncthreads();
  const int n = t & 15, ck = t >> 4;
  float acc = 0.f;
  const float* hrow = hs + ck * 64;
  const float* wcol = w2 + (size_t)(ck * 64) * 16 + n;
#pragma unroll 8
  for (int k = 0; k < 64; k++) acc += hrow[k] * wcol[k * 16];
  red[t] = acc;
  __syncthreads();
  if (t < 16) {
    float s2 = 0.f;
#pragma unroll
    for (int c = 0; c < 16; c++) s2 += red[c * 16 + t];
    btab[(size_t)t * NSEQ + r] = s2 + b2[t];
  }
}

// ---------------- per-head static max + pre-scaled bias table ---------------
__global__ __launch_bounds__(256) void bmax_k(const float* __restrict__ btab,
                                              const float* __restrict__ nbias,
                                              float* __restrict__ btab2,
                                              float* __restrict__ mh) {
  const int h = blockIdx.x, t = threadIdx.x;
  const float* src = btab + (size_t)h * 2048;
  float mx = -3e38f;
  for (int j = t; j < 2048; j += 256) mx = fmaxf(mx, src[j]);
  mx = fmaxf(mx, __shfl_xor(mx, 1));  mx = fmaxf(mx, __shfl_xor(mx, 2));
  mx = fmaxf(mx, __shfl_xor(mx, 4));  mx = fmaxf(mx, __shfl_xor(mx, 8));
  mx = fmaxf(mx, __shfl_xor(mx, 16)); mx = fmaxf(mx, __shfl_xor(mx, 32));
  __shared__ float red[4];
  if ((t & 63) == 0) red[t >> 6] = mx;
  __syncthreads();
  float m = fmaxf(fmaxf(red[0], red[1]), fmaxf(red[2], red[3]));
  m = 8.25f + fmaxf(m, nbias[h]);
  if (t == 0) mh[h] = m;
  float* dst = btab2 + (size_t)h * 2048;
  for (int j = t; j < 2048; j += 256) dst[j] = (src[j] - m) * 1.44269504f;
}

// ---------------- fused qkv-GEMM (288 blocks) + w1-GEMM (128 blocks) --------
__global__ __launch_bounds__(256, 2) void gemm2_k(const short* __restrict__ xn,
                                                  const short* __restrict__ wqkvT,
                                                  const short* __restrict__ h0,
                                                  const short* __restrict__ w1T,
                                                  float* __restrict__ h1t,
                                                  const float* __restrict__ b1,
                                                  const float* __restrict__ qs,
                                                  const float* __restrict__ ks,
                                                  short* __restrict__ qb,
                                                  short* __restrict__ kb,
                                                  short* __restrict__ vtb) {
  __shared__ __align__(16) short Al[2][128 * 32];
  __shared__ __align__(16) short Bl[2][128 * 32];
  const int tid = threadIdx.x;
  const int lane = tid & 63;
  const int l15 = lane & 15, l4 = lane >> 4;
  const int wid = tid >> 6;
  const int wr = wid >> 1, wc = wid & 1;
  const int bid = blockIdx.x;
  const bool isqkv = bid < 288;
  const short* A; const short* Bm; int rowa0, rowb0;
  if (isqkv) { A = xn; Bm = wqkvT; rowa0 = (bid & 31) * 128; rowb0 = (bid >> 5) * 128; }
  else { const int idx = bid - 288; A = h0; Bm = w1T; rowa0 = (idx & 15) * 128; rowb0 = (idx >> 4) * 128; }
  const int K = 1024;
  f32x4 acc[4][4];
#pragma unroll
  for (int m = 0; m < 4; m++)
#pragma unroll
    for (int n = 0; n < 4; n++) acc[m][n] = (f32x4){0.f, 0.f, 0.f, 0.f};

  const int sr = tid >> 2, sc = (tid & 3) * 8;
  const short* ga = A  + (size_t)(rowa0 + sr) * K + sc;
  const short* gb = Bm + (size_t)(rowb0 + sr) * K + sc;

  auto stage = [&](int buf, int k0) {
    char* la = (char*)Al[buf] + wid * 1024;
    char* lb = (char*)Bl[buf] + wid * 1024;
    async_lds16(ga + k0,                  la);
    async_lds16(ga + (size_t)64 * K + k0, la + 4096);
    async_lds16(gb + k0,                  lb);
    async_lds16(gb + (size_t)64 * K + k0, lb + 4096);
  };

  stage(0, 0);
  int cur = 0;
  for (int k0 = 0; k0 < K; k0 += 32) {
    __syncthreads();
    if (k0 + 32 < K) stage(cur ^ 1, k0 + 32);
    s16x8 af[4], bfr[4];
#pragma unroll
    for (int m = 0; m < 4; m++)
      af[m] = *(const s16x8*)&Al[cur][(wr * 64 + m * 16 + l15) * 32 + l4 * 8];
#pragma unroll
    for (int n = 0; n < 4; n++)
      bfr[n] = *(const s16x8*)&Bl[cur][(wc * 64 + n * 16 + l15) * 32 + l4 * 8];
#pragma unroll
    for (int m = 0; m < 4; m++)
#pragma unroll
      for (int n = 0; n < 4; n++)
        acc[m][n] = __builtin_amdgcn_mfma_f32_16x16x32_bf16(af[m], bfr[n], acc[m][n], 0, 0, 0);
    cur ^= 1;
  }

  const int colbase = rowb0 + wc * 64;
  const int rowg0 = rowa0 + wr * 64;
  if (!isqkv) {
#pragma unroll
    for (int n = 0; n < 4; n++) {
      const int col = colbase + n * 16 + l15;
      const float bv = b1[col];
#pragma unroll
      for (int m = 0; m < 4; m++) {
        const int row = rowg0 + m * 16 + l4 * 4;
#pragma unroll
        for (int j = 0; j < 4; j++)
          h1t[(size_t)(row + j) * 1024 + col] = acc[m][n][j] + bv;
      }
    }
  } else if (colbase < 1024 || wc == 0) {
    // q (cols<1024) or k (1024..1087): row-wise l2norm over 64 cols
    const bool isq = (colbase < 1024);
    const float* scp = isq ? qs : ks;
#pragma unroll
    for (int m = 0; m < 4; m++) {
      float inv[4];
#pragma unroll
      for (int jj = 0; jj < 4; jj++) {
        float ssq = 0.f;
#pragma unroll
        for (int n = 0; n < 4; n++) ssq += acc[m][n][jj] * acc[m][n][jj];
        ssq += __shfl_xor(ssq, 1); ssq += __shfl_xor(ssq, 2);
        ssq += __shfl_xor(ssq, 4); ssq += __shfl_xor(ssq, 8);
        inv[jj] = 1.f / fmaxf(sqrtf(ssq), 1e-12f);
      }
#pragma unroll
      for (int n = 0; n < 4; n++) {
        const int d = n * 16 + l15;
        const float sc2 = scp[d];
#pragma unroll
        for (int jj = 0; jj < 4; jj++) {
          const int row = rowg0 + m * 16 + l4 * 4 + jj;
          const short v = f2bf(acc[m][n][jj] * inv[jj] * sc2);
          if (isq) qb[(size_t)row * 1024 + colbase + d] = v;
          else     kb[(size_t)row * 64 + d] = v;
        }
      }
    }
  } else {
    // v (cols 1088..1151): transposed bf16 store
#pragma unroll
    for (int m = 0; m < 4; m++)
#pragma unroll
      for (int n = 0; n < 4; n++) {
        const int d = n * 16 + l15;
        const int row = rowg0 + m * 16 + l4 * 4;
        const int bb = row >> 11, ii = row & 2047;
        s16x4 o;
#pragma unroll
        for (int jj = 0; jj < 4; jj++) o[jj] = f2bf(acc[m][n][jj]);
        *(s16x4*)(vtb + ((size_t)(bb * 64 + d)) * 2048 + ii) = o;
      }
  }
}

// ---------------- GEMM (out-projection): C = A * Bm^T -----------------------
__global__ __launch_bounds__(256, 2) void gemm_bt(const short* __restrict__ A,
                                                  const short* __restrict__ Bm,
                                                  float* __restrict__ C,
                                                  int M, int N, int K) {
  __shared__ __align__(16) short Al[2][128 * 32];
  __shared__ __align__(16) short Bl[2][128 * 32];
  const int tid = threadIdx.x;
  const int lane = tid & 63;
  const int l15 = lane & 15, l4 = lane >> 4;
  const int wid = tid >> 6;
  const int wr = wid >> 1, wc = wid & 1;
  const int rowa0 = blockIdx.x * 128, rowb0 = blockIdx.y * 128;
  f32x4 acc[4][4];
#pragma unroll
  for (int m = 0; m < 4; m++)
#pragma unroll
    for (int n = 0; n < 4; n++) acc[m][n] = (f32x4){0.f, 0.f, 0.f, 0.f};

  const int sr = tid >> 2, sc = (tid & 3) * 8;
  const short* ga = A  + (size_t)(rowa0 + sr) * K + sc;
  const short* gb = Bm + (size_t)(rowb0 + sr) * K + sc;

  auto stage = [&](int buf, int k0) {
    char* la = (char*)Al[buf] + wid * 1024;
    char* lb = (char*)Bl[buf] + wid * 1024;
    async_lds16(ga + k0,                  la);
    async_lds16(ga + (size_t)64 * K + k0, la + 4096);
    async_lds16(gb + k0,                  lb);
    async_lds16(gb + (size_t)64 * K + k0, lb + 4096);
  };

  stage(0, 0);
  int cur = 0;
  for (int k0 = 0; k0 < K; k0 += 32) {
    __syncthreads();
    if (k0 + 32 < K) stage(cur ^ 1, k0 + 32);
    s16x8 af[4], bfr[4];
#pragma unroll
    for (int m = 0; m < 4; m++)
      af[m] = *(const s16x8*)&Al[cur][(wr * 64 + m * 16 + l15) * 32 + l4 * 8];
#pragma unroll
    for (int n = 0; n < 4; n++)
      bfr[n] = *(const s16x8*)&Bl[cur][(wc * 64 + n * 16 + l15) * 32 + l4 * 8];
#pragma unroll
    for (int m = 0; m < 4; m++)
#pragma unroll
      for (int n = 0; n < 4; n++)
        acc[m][n] = __builtin_amdgcn_mfma_f32_16x16x32_bf16(af[m], bfr[n], acc[m][n], 0, 0, 0);
    cur ^= 1;
  }
#pragma unroll
  for (int n = 0; n < 4; n++) {
    const int col = rowb0 + wc * 64 + n * 16 + l15;
#pragma unroll
    for (int m = 0; m < 4; m++) {
      const int row = rowa0 + wr * 64 + m * 16 + l4 * 4;
#pragma unroll
      for (int j = 0; j < 4; j++)
        C[(size_t)(row + j) * N + col] = acc[m][n][j];
    }
  }
}

// ---------------- flash attention v5: swapped QK^T, in-register P -----------
// mfma(K,Q) puts P[key=l4*4+jj][q=l15] per lane: row-sum = local + 2 shfl_xor;
// P->bf16 via v_cvt_pk_bf16_f32; PV A-fragment assembled with 16 shfl + 8 sel
// (no P LDS roundtrip, no ones-MFMA). K/V double-buffered in LDS as in v4.
__global__ __launch_bounds__(256, 3) void attn_k(const short* __restrict__ q,
                                                 const short* __restrict__ kk,
                                                 const short* __restrict__ vt,
                                                 const float* __restrict__ btab2,
                                                 const float* __restrict__ mh,
                                                 const float* __restrict__ nkv,
                                                 const float* __restrict__ nbias,
                                                 const float* __restrict__ kscale,
                                                 short* __restrict__ aout) {
  __shared__ __align__(16) short Kl[2][64 * 64];   // 16 KB, swizzled [key][d]
  __shared__ __align__(16) short Vl[2][64 * 64];   // 16 KB, swizzled [d][key]
  __shared__ __align__(16) float btl[2048];        // 8 KB bias row
  __shared__ float nkn[64], nvv[64];

  const int tid = threadIdx.x;
  const int w = tid >> 6, lane = tid & 63;
  const int l15 = lane & 15, l4 = lane >> 4;
  const int bid = blockIdx.x;
  const int b = bid & 1, h = (bid >> 1) & 15, qt = 31 - (bid >> 5);
  const int i0 = qt * 64;
  const int nt = qt + 1;
  const int qrow0 = i0 + w * 16;

  const float* bsrc = btab2 + (size_t)h * 2048;
  async_lds16(bsrc + w * 256 + lane * 4,        (char*)btl + w * 1024);
  async_lds16(bsrc + 1024 + w * 256 + lane * 4, (char*)btl + 4096 + w * 1024);

  const int sr = tid >> 3;
  const int sb = (tid & 7) ^ (sr & 7);
  const short* gk = kk + ((size_t)(b * NSEQ) + sr) * DH + sb * 8;
  const short* gv = vt + ((size_t)b * DH + sr) * NSEQ + sb * 8;

  async_lds16(gk,             (char*)Kl[0] + w * 1024);
  async_lds16(gk + 32 * DH,   (char*)Kl[0] + 4096 + w * 1024);
  async_lds16(gv,             (char*)Vl[0] + w * 1024);
  async_lds16(gv + 32 * NSEQ, (char*)Vl[0] + 4096 + w * 1024);

  if (w == 0) {
    float kx = nkv[lane];
    float ssn = wave_sum(kx * kx);
    nkn[lane] = kx / fmaxf(sqrtf(ssn), 1e-12f) * kscale[lane];
    nvv[lane] = nkv[64 + lane];
  }
  const short* qbase = q + (size_t)(b * NSEQ + qrow0) * DIMM + h * DH;
  s16x8 qf0 = *(const s16x8*)(qbase + (size_t)l15 * DIMM + l4 * 8);
  s16x8 qf1 = *(const s16x8*)(qbase + (size_t)l15 * DIMM + 32 + l4 * 8);
  const float m = mh[h];
  __syncthreads();

  // null-token init (per lane l15 = q-row)
  float sn = 0.f;
#pragma unroll
  for (int j = 0; j < 8; j++)
    sn += bf2f(qf0[j]) * nkn[l4 * 8 + j] + bf2f(qf1[j]) * nkn[32 + l4 * 8 + j];
  sn += __shfl_xor(sn, 16);
  sn += __shfl_xor(sn, 32);
  const float pnc = __builtin_amdgcn_exp2f(fmaf(sn, 11.5415603f,
                                                (nbias[h] - m) * 1.44269504f));
  float den[4];
  f32x4 o[4];
#pragma unroll
  for (int jj = 0; jj < 4; jj++) den[jj] = __shfl(pnc, l4 * 4 + jj);
#pragma unroll
  for (int dg = 0; dg < 4; dg++) {
    float nv = nvv[dg * 16 + l15];
#pragma unroll
    for (int jj = 0; jj < 4; jj++) o[dg][jj] = den[jj] * nv;
  }

  const int s1l = ((l4 & 1) << 5) + l15;   // source lane 1 for PV A-frag
  const int hi  = (l4 >> 1) & 1;
  int cur = 0;

  for (int t = 0; t < nt; ++t) {
    if (t + 1 < nt) {
      const int jn = (t + 1) * 64;
      async_lds16(gk + (size_t)jn * DH,        (char*)Kl[cur ^ 1] + w * 1024);
      async_lds16(gk + (size_t)(jn + 32) * DH, (char*)Kl[cur ^ 1] + 4096 + w * 1024);
      async_lds16(gv + jn,                     (char*)Vl[cur ^ 1] + w * 1024);
      async_lds16(gv + 32 * NSEQ + jn,         (char*)Vl[cur ^ 1] + 4096 + w * 1024);
    }
    const int j0 = t * 64;
    // QK^T swapped: A = K-frag, B = Q-frag  ->  lane holds P[key=l4*4+jj][q=l15]
    f32x4 s[4];
#pragma unroll
    for (int kb2 = 0; kb2 < 4; kb2++) s[kb2] = (f32x4){0.f, 0.f, 0.f, 0.f};
#pragma unroll
    for (int c = 0; c < 2; c++) {
#pragma unroll
      for (int kb2 = 0; kb2 < 4; kb2++) {
        const int key = kb2 * 16 + l15;
        s16x8 kf = *(const s16x8*)((const char*)Kl[cur] + key * 128 +
                                   ((((c << 2) + l4) ^ (key & 7)) << 4));
        s[kb2] = __builtin_amdgcn_mfma_f32_16x16x32_bf16(kf, c == 0 ? qf0 : qf1, s[kb2], 0, 0, 0);
      }
    }
    // softmax in-register; q = l15, key = j0 + kb2*16 + l4*4 + jj
    float p[4][4];
    float loc = 0.f;
#pragma unroll
    for (int kb2 = 0; kb2 < 4; kb2++) {
#pragma unroll
      for (int jj = 0; jj < 4; jj++) {
        const int rel = (qrow0 + l15) - (j0 + kb2 * 16 + l4 * 4 + jj);
        const float bb = btl[rel & 2047];
        const float sv = fmaf(s[kb2][jj], 11.5415603f, bb);
        const float pp = (rel >= 0) ? __builtin_amdgcn_exp2f(sv) : 0.f;
        p[kb2][jj] = pp;
        loc += pp;
      }
    }
    loc += __shfl_xor(loc, 16);
    loc += __shfl_xor(loc, 32);
#pragma unroll
    for (int jj = 0; jj < 4; jj++) den[jj] += __shfl(loc, l4 * 4 + jj);
    // pack P to bf16 pairs
    unsigned pk[4][2];
#pragma unroll
    for (int kb2 = 0; kb2 < 4; kb2++) {
      pk[kb2][0] = cvtpk_bf16(p[kb2][0], p[kb2][1]);
      pk[kb2][1] = cvtpk_bf16(p[kb2][2], p[kb2][3]);
    }
    // PV: assemble A-frag per c via shfl, B = V-frag from LDS
#pragma unroll
    for (int c = 0; c < 2; c++) {
      const int a00 = __shfl((int)pk[2 * c][0],     s1l);
      const int a01 = __shfl((int)pk[2 * c][1],     s1l);
      const int a10 = __shfl((int)pk[2 * c + 1][0], s1l);
      const int a11 = __shfl((int)pk[2 * c + 1][1], s1l);
      const int b00 = __shfl((int)pk[2 * c][0],     s1l + 16);
      const int b01 = __shfl((int)pk[2 * c][1],     s1l + 16);
      const int b10 = __shfl((int)pk[2 * c + 1][0], s1l + 16);
      const int b11 = __shfl((int)pk[2 * c + 1][1], s1l + 16);
      union { int i[4]; s16x8 v; } pu;
      pu.i[0] = hi ? a10 : a00;
      pu.i[1] = hi ? a11 : a01;
      pu.i[2] = hi ? b10 : b00;
      pu.i[3] = hi ? b11 : b01;
      const int slice = c * 4 + l4;
#pragma unroll
      for (int dg = 0; dg < 4; dg++) {
        const int d = dg * 16 + l15;
        s16x8 vf = *(const s16x8*)((const char*)Vl[cur] + d * 128 +
                                   ((slice ^ (d & 7)) << 4));
        o[dg] = __builtin_amdgcn_mfma_f32_16x16x32_bf16(pu.v, vf, o[dg], 0, 0, 0);
      }
    }
    __syncthreads();
    cur ^= 1;
  }

  // epilogue: reuse Kl (dead) as per-wave f32 staging for coalesced store
  float* ob = (float*)Kl + w * 1024;
#pragma unroll
  for (int dg = 0; dg < 4; dg++)
#pragma unroll
    for (int jj = 0; jj < 4; jj++)
      ob[(l4 * 4 + jj) * 64 + dg * 16 + l15] = o[dg][jj] / den[jj];
  const int orow = lane >> 2, oc = (lane & 3) * 16;
  const float* srcp = ob + orow * 64 + oc;
  s16x8 r0, r1;
#pragma unroll
  for (int j = 0; j < 8; j++) { r0[j] = f2bf(srcp[j]); r1[j] = f2bf(srcp[8 + j]); }
  short* gout = aout + (size_t)(b * NSEQ + i0 + w * 16 + orow) * DIMM + h * DH + oc;
  *(s16x8*)gout = r0;
  *(s16x8*)(gout + 8) = r1;
}

// ---------------- final row LayerNorm ---------------------------------------
__global__ __launch_bounds__(256) void final_ln_k(const float* __restrict__ in,
                                                  const float* __restrict__ gamma,
                                                  float* __restrict__ of) {
  const int r = blockIdx.x, t = threadIdx.x;
  float4 x = *(const float4*)(in + (size_t)r * 1024 + t * 4);
  float v[4] = {x.x, x.y, x.z, x.w};
  float s  = v[0] + v[1] + v[2] + v[3];
  float ss = v[0]*v[0] + v[1]*v[1] + v[2]*v[2] + v[3]*v[3];
  s = wave_sum(s); ss = wave_sum(ss);
  __shared__ float rb[8];
  const int w = t >> 6, ln = t & 63;
  if (ln == 0) { rb[w] = s; rb[4 + w] = ss; }
  __syncthreads();
  s  = rb[0] + rb[1] + rb[2] + rb[3];
  ss = rb[4] + rb[5] + rb[6] + rb[7];
  const float mean = s * (1.f / 1024.f);
  const float inv  = rsqrtf(ss * (1.f / 1024.f) - mean * mean + 1e-5f);
  float4 gx = *(const float4*)(gamma + t * 4);
  float gg[4] = {gx.x, gx.y, gx.z, gx.w};
  float4 o;
  o.x = (v[0] - mean) * inv * gg[0];
  o.y = (v[1] - mean) * inv * gg[1];
  o.z = (v[2] - mean) * inv * gg[2];
  o.w = (v[3] - mean) * inv * gg[3];
  *(float4*)(of + (size_t)r * 1024 + t * 4) = o;
}

// ---------------------------------------------------------------------------
extern "C" void kernel_launch(void* const* d_in, const int* in_sizes, int n_in,
                              void* d_out, int out_size, void* d_ws, size_t ws_size,
                              hipStream_t stream) {
  const float* x       = (const float*)d_in[0];
  const float* g_norm  = (const float*)d_in[2];
  const float* Wq      = (const float*)d_in[3];
  const float* Wkv     = (const float*)d_in[4];
  const float* q_scale = (const float*)d_in[5];
  const float* k_scale = (const float*)d_in[6];
  const float* null_kv = (const float*)d_in[7];
  const float* nbias   = (const float*)d_in[8];
  const float* w0      = (const float*)d_in[9];
  const float* b0      = (const float*)d_in[10];
  const float* g0      = (const float*)d_in[11];
  const float* w1      = (const float*)d_in[12];
  const float* b1      = (const float*)d_in[13];
  const float* g1      = (const float*)d_in[14];
  const float* w2      = (const float*)d_in[15];
  const float* b2      = (const float*)d_in[16];
  const float* Wout    = (const float*)d_in[17];
  const float* g_out   = (const float*)d_in[18];

  char* p = (char*)d_ws;
  auto alloc = [&](size_t bytes) {
    char* r = p; p += (bytes + 255) & ~(size_t)255; return r;
  };
  short* xn     = (short*)alloc((size_t)4096 * 1024 * 2);
  short* wqkvT  = (short*)alloc((size_t)1152 * 1024 * 2);
  short* w1T    = (short*)alloc((size_t)1024 * 1024 * 2);
  short* woT    = (short*)alloc((size_t)1024 * 1024 * 2);
  short* qb     = (short*)alloc((size_t)4096 * 1024 * 2);
  short* kbuf   = (short*)alloc((size_t)2 * NSEQ * DH * 2);
  short* vtb    = (short*)alloc((size_t)2 * DH * NSEQ * 2);
  short* h0     = (short*)alloc((size_t)2048 * 1024 * 2);
  float* btab   = (float*)alloc((size_t)16 * NSEQ * 4);
  float* btab2  = (float*)alloc((size_t)16 * NSEQ * 4);
  float* mh     = (float*)alloc(16 * 4);
  float* opre   = (float*)alloc((size_t)4096 * 1024 * 4);  // 16.8 MB
  // time-sliced aliases:
  float* h1t  = opre;            // bias-MLP h1 pre-LN (dead before out-proj)
  short* aout = xn;              // attn output (xn dead after qkv gemm)

  // 1: transposes + LN(x) + layer0 in one launch
  prep_k<<<9344, 256, 0, stream>>>(x, g_norm, w0, b0, g0, Wq, Wkv, w1, Wout,
                                   xn, h0, wqkvT, w1T, woT);
  // 2: qkv projection (+l2norm/transpose epilogue) and w1 GEMM, one launch
  gemm2_k<<<416, 256, 0, stream>>>(xn, wqkvT, h0, w1T, h1t, b1,
                                   q_scale, k_scale, qb, kbuf, vtb);
  // 3: LN+silu fused into btab
  btab_k<<<2048, 256, 0, stream>>>(h1t, g1, w2, b2, btab);
  // 4: per-head static max + prescaled bias
  bmax_k<<<16, 256, 0, stream>>>(btab, nbias, btab2, mh);
  // 5: flash attention (LPT grid)
  attn_k<<<dim3(1024), 256, 0, stream>>>(qb, kbuf, vtb, btab2, mh, null_kv, nbias,
                                         k_scale, aout);
  // 6: output projection
  gemm_bt<<<dim3(32, 8), 256, 0, stream>>>(aout, woT, opre, 4096, 1024, 1024);
  // 7: final LN
  final_ln_k<<<4096, 256, 0, stream>>>(opre, g_out, (float*)d_out);
}

// Round 7
// 137.396 us; speedup vs baseline: 2.4457x; 1.0225x over previous
//
#include <hip/hip_runtime.h>

#define NSEQ 2048
#define DIMM 1024
#define NH   16
#define DH   64

using f32x4 = __attribute__((ext_vector_type(4))) float;
using s16x8 = __attribute__((ext_vector_type(8))) short;
using s16x4 = __attribute__((ext_vector_type(4))) short;

__device__ __forceinline__ short f2bf(float f) {
  union { float f; unsigned u; } a; a.f = f;
  unsigned r = (a.u + 0x7fffu + ((a.u >> 16) & 1u)) >> 16;
  return (short)(unsigned short)r;
}
__device__ __forceinline__ float bf2f(short s) {
  union { float f; unsigned u; } a; a.u = ((unsigned)(unsigned short)s) << 16;
  return a.f;
}
__device__ __forceinline__ unsigned cvtpk_bf16(float lo, float hi) {
  unsigned r;
  asm("v_cvt_pk_bf16_f32 %0, %1, %2" : "=v"(r) : "v"(lo), "v"(hi));
  return r;
}

__device__ __forceinline__ void async_lds16(const void* g, void* l) {
  __builtin_amdgcn_global_load_lds(
      (const __attribute__((address_space(1))) void*)g,
      (__attribute__((address_space(3))) void*)l, 16, 0, 0);
}

__device__ __forceinline__ float wave_sum(float v) {
  v += __shfl_xor(v, 1);  v += __shfl_xor(v, 2);  v += __shfl_xor(v, 4);
  v += __shfl_xor(v, 8);  v += __shfl_xor(v, 16); v += __shfl_xor(v, 32);
  return v;
}

// ---------------- prep: 4 weight transposes + LN(x) + bias-MLP layer0 -------
__global__ __launch_bounds__(256) void prep_k(const float* __restrict__ x,
                                              const float* __restrict__ g_norm,
                                              const float* __restrict__ w0,
                                              const float* __restrict__ b0,
                                              const float* __restrict__ g0,
                                              const float* __restrict__ Wq,
                                              const float* __restrict__ Wkv,
                                              const float* __restrict__ w1,
                                              const float* __restrict__ Wout,
                                              short* __restrict__ xn,
                                              short* __restrict__ h0,
                                              short* __restrict__ wqkvT,
                                              short* __restrict__ w1T,
                                              short* __restrict__ woT) {
  __shared__ float tile[32][33];
  __shared__ float rb[8];
  const int bid = blockIdx.x, t = threadIdx.x;
  if (bid < 3200) {
    const float* W; short* Wt; int N, bx, by;
    if (bid < 1024)      { W = Wq;   Wt = wqkvT;                       N = 1024; bx = bid & 31;          by = bid >> 5; }
    else if (bid < 1152) { W = Wkv;  Wt = wqkvT + (size_t)1024 * 1024; N = 128;  bx = (bid - 1024) & 3;  by = (bid - 1024) >> 2; }
    else if (bid < 2176) { W = w1;   Wt = w1T;                         N = 1024; bx = (bid - 1152) & 31; by = (bid - 1152) >> 5; }
    else                 { W = Wout; Wt = woT;                         N = 1024; bx = (bid - 2176) & 31; by = (bid - 2176) >> 5; }
    const int n0 = bx * 32, k0 = by * 32;
    const int tx = t & 31, ty = t >> 5;
#pragma unroll
    for (int r = 0; r < 32; r += 8)
      tile[ty + r][tx] = W[(size_t)(k0 + ty + r) * N + n0 + tx];
    __syncthreads();
#pragma unroll
    for (int r = 0; r < 32; r += 8)
      Wt[(size_t)(n0 + ty + r) * 1024 + k0 + tx] = f2bf(tile[tx][ty + r]);
    return;
  }
  const bool isln = (bid < 7296);
  const int r = isln ? (bid - 3200) : (bid - 7296);
  float v[4];
  if (isln) {
    float4 xv = *(const float4*)(x + (size_t)r * 1024 + t * 4);
    v[0] = xv.x; v[1] = xv.y; v[2] = xv.z; v[3] = xv.w;
  } else {
    const float p = (float)r;
    float4 wv = *(const float4*)(w0 + t * 4);
    float4 bv = *(const float4*)(b0 + t * 4);
    v[0] = p * wv.x + bv.x; v[1] = p * wv.y + bv.y;
    v[2] = p * wv.z + bv.z; v[3] = p * wv.w + bv.w;
  }
  float s  = v[0] + v[1] + v[2] + v[3];
  float ss = v[0]*v[0] + v[1]*v[1] + v[2]*v[2] + v[3]*v[3];
  s = wave_sum(s); ss = wave_sum(ss);
  const int w = t >> 6, ln = t & 63;
  if (ln == 0) { rb[w] = s; rb[4 + w] = ss; }
  __syncthreads();
  s  = rb[0] + rb[1] + rb[2] + rb[3];
  ss = rb[4] + rb[5] + rb[6] + rb[7];
  const float mean = s * (1.f / 1024.f);
  const float inv  = rsqrtf(ss * (1.f / 1024.f) - mean * mean + 1e-5f);
  const float* gp = isln ? g_norm : g0;
  float4 gx = *(const float4*)(gp + t * 4);
  float gg[4] = {gx.x, gx.y, gx.z, gx.w};
  s16x4 o;
#pragma unroll
  for (int j = 0; j < 4; j++) {
    float y = (v[j] - mean) * inv * gg[j];
    if (!isln) y = y / (1.f + __expf(-y));
    o[j] = f2bf(y);
  }
  short* dst = isln ? xn : h0;
  *(s16x4*)(dst + (size_t)r * 1024 + t * 4) = o;
}

// ---------------- btab: LN+silu of h1t rows fused with @ w2 + b2 ------------
__global__ __launch_bounds__(256) void btab_k(const float* __restrict__ h1t,
                                              const float* __restrict__ g1,
                                              const float* __restrict__ w2,
                                              const float* __restrict__ b2,
                                              float* __restrict__ btab) {
  __shared__ float hs[1024];
  __shared__ float rb[8];
  __shared__ float red[256];
  const int r = blockIdx.x, t = threadIdx.x;
  float4 xv = *(const float4*)(h1t + (size_t)r * 1024 + t * 4);
  float v[4] = {xv.x, xv.y, xv.z, xv.w};
  float s  = v[0] + v[1] + v[2] + v[3];
  float ss = v[0]*v[0] + v[1]*v[1] + v[2]*v[2] + v[3]*v[3];
  s = wave_sum(s); ss = wave_sum(ss);
  const int w = t >> 6, ln = t & 63;
  if (ln == 0) { rb[w] = s; rb[4 + w] = ss; }
  __syncthreads();
  s  = rb[0] + rb[1] + rb[2] + rb[3];
  ss = rb[4] + rb[5] + rb[6] + rb[7];
  const float mean = s * (1.f / 1024.f);
  const float inv  = rsqrtf(ss * (1.f / 1024.f) - mean * mean + 1e-5f);
  float4 gx = *(const float4*)(g1 + t * 4);
  float gg[4] = {gx.x, gx.y, gx.z, gx.w};
#pragma unroll
  for (int j = 0; j < 4; j++) {
    float y = (v[j] - mean) * inv * gg[j];
    hs[t * 4 + j] = y / (1.f + __expf(-y));
  }
  __syncthreads();
  const int n = t & 15, ck = t >> 4;
  float acc = 0.f;
  const float* hrow = hs + ck * 64;
  const float* wcol = w2 + (size_t)(ck * 64) * 16 + n;
#pragma unroll 8
  for (int k = 0; k < 64; k++) acc += hrow[k] * wcol[k * 16];
  red[t] = acc;
  __syncthreads();
  if (t < 16) {
    float s2 = 0.f;
#pragma unroll
    for (int c = 0; c < 16; c++) s2 += red[c * 16 + t];
    btab[(size_t)t * NSEQ + r] = s2 + b2[t];
  }
}

// ---------------- per-head static max + pre-scaled bias table (bf16 out) ----
__global__ __launch_bounds__(256) void bmax_k(const float* __restrict__ btab,
                                              const float* __restrict__ nbias,
                                              unsigned short* __restrict__ btab2,
                                              float* __restrict__ mh) {
  const int h = blockIdx.x, t = threadIdx.x;
  const float* src = btab + (size_t)h * 2048;
  float mx = -3e38f;
  for (int j = t; j < 2048; j += 256) mx = fmaxf(mx, src[j]);
  mx = fmaxf(mx, __shfl_xor(mx, 1));  mx = fmaxf(mx, __shfl_xor(mx, 2));
  mx = fmaxf(mx, __shfl_xor(mx, 4));  mx = fmaxf(mx, __shfl_xor(mx, 8));
  mx = fmaxf(mx, __shfl_xor(mx, 16)); mx = fmaxf(mx, __shfl_xor(mx, 32));
  __shared__ float red[4];
  if ((t & 63) == 0) red[t >> 6] = mx;
  __syncthreads();
  float m = fmaxf(fmaxf(red[0], red[1]), fmaxf(red[2], red[3]));
  m = 8.25f + fmaxf(m, nbias[h]);
  if (t == 0) mh[h] = m;
  unsigned short* dst = btab2 + (size_t)h * 2048;
  for (int j = t; j < 2048; j += 256)
    dst[j] = (unsigned short)f2bf((src[j] - m) * 1.44269504f);
}

// ---------------- fused qkv-GEMM (288 blocks) + w1-GEMM (128 blocks) --------
__global__ __launch_bounds__(256, 2) void gemm2_k(const short* __restrict__ xn,
                                                  const short* __restrict__ wqkvT,
                                                  const short* __restrict__ h0,
                                                  const short* __restrict__ w1T,
                                                  float* __restrict__ h1t,
                                                  const float* __restrict__ b1,
                                                  const float* __restrict__ qs,
                                                  const float* __restrict__ ks,
                                                  short* __restrict__ qb,
                                                  short* __restrict__ kb,
                                                  short* __restrict__ vtb) {
  __shared__ __align__(16) short Al[2][128 * 32];
  __shared__ __align__(16) short Bl[2][128 * 32];
  const int tid = threadIdx.x;
  const int lane = tid & 63;
  const int l15 = lane & 15, l4 = lane >> 4;
  const int wid = tid >> 6;
  const int wr = wid >> 1, wc = wid & 1;
  const int bid = blockIdx.x;
  const bool isqkv = bid < 288;
  const short* A; const short* Bm; int rowa0, rowb0;
  if (isqkv) { A = xn; Bm = wqkvT; rowa0 = (bid & 31) * 128; rowb0 = (bid >> 5) * 128; }
  else { const int idx = bid - 288; A = h0; Bm = w1T; rowa0 = (idx & 15) * 128; rowb0 = (idx >> 4) * 128; }
  const int K = 1024;
  f32x4 acc[4][4];
#pragma unroll
  for (int m = 0; m < 4; m++)
#pragma unroll
    for (int n = 0; n < 4; n++) acc[m][n] = (f32x4){0.f, 0.f, 0.f, 0.f};

  const int sr = tid >> 2, sc = (tid & 3) * 8;
  const short* ga = A  + (size_t)(rowa0 + sr) * K + sc;
  const short* gb = Bm + (size_t)(rowb0 + sr) * K + sc;

  auto stage = [&](int buf, int k0) {
    char* la = (char*)Al[buf] + wid * 1024;
    char* lb = (char*)Bl[buf] + wid * 1024;
    async_lds16(ga + k0,                  la);
    async_lds16(ga + (size_t)64 * K + k0, la + 4096);
    async_lds16(gb + k0,                  lb);
    async_lds16(gb + (size_t)64 * K + k0, lb + 4096);
  };

  stage(0, 0);
  int cur = 0;
  for (int k0 = 0; k0 < K; k0 += 32) {
    __syncthreads();
    if (k0 + 32 < K) stage(cur ^ 1, k0 + 32);
    s16x8 af[4], bfr[4];
#pragma unroll
    for (int m = 0; m < 4; m++)
      af[m] = *(const s16x8*)&Al[cur][(wr * 64 + m * 16 + l15) * 32 + l4 * 8];
#pragma unroll
    for (int n = 0; n < 4; n++)
      bfr[n] = *(const s16x8*)&Bl[cur][(wc * 64 + n * 16 + l15) * 32 + l4 * 8];
#pragma unroll
    for (int m = 0; m < 4; m++)
#pragma unroll
      for (int n = 0; n < 4; n++)
        acc[m][n] = __builtin_amdgcn_mfma_f32_16x16x32_bf16(af[m], bfr[n], acc[m][n], 0, 0, 0);
    cur ^= 1;
  }

  const int colbase = rowb0 + wc * 64;
  const int rowg0 = rowa0 + wr * 64;
  if (!isqkv) {
#pragma unroll
    for (int n = 0; n < 4; n++) {
      const int col = colbase + n * 16 + l15;
      const float bv = b1[col];
#pragma unroll
      for (int m = 0; m < 4; m++) {
        const int row = rowg0 + m * 16 + l4 * 4;
#pragma unroll
        for (int j = 0; j < 4; j++)
          h1t[(size_t)(row + j) * 1024 + col] = acc[m][n][j] + bv;
      }
    }
  } else if (colbase < 1024 || wc == 0) {
    const bool isq = (colbase < 1024);
    const float* scp = isq ? qs : ks;
#pragma unroll
    for (int m = 0; m < 4; m++) {
      float inv[4];
#pragma unroll
      for (int jj = 0; jj < 4; jj++) {
        float ssq = 0.f;
#pragma unroll
        for (int n = 0; n < 4; n++) ssq += acc[m][n][jj] * acc[m][n][jj];
        ssq += __shfl_xor(ssq, 1); ssq += __shfl_xor(ssq, 2);
        ssq += __shfl_xor(ssq, 4); ssq += __shfl_xor(ssq, 8);
        inv[jj] = 1.f / fmaxf(sqrtf(ssq), 1e-12f);
      }
#pragma unroll
      for (int n = 0; n < 4; n++) {
        const int d = n * 16 + l15;
        const float sc2 = scp[d];
#pragma unroll
        for (int jj = 0; jj < 4; jj++) {
          const int row = rowg0 + m * 16 + l4 * 4 + jj;
          const short v = f2bf(acc[m][n][jj] * inv[jj] * sc2);
          if (isq) qb[(size_t)row * 1024 + colbase + d] = v;
          else     kb[(size_t)row * 64 + d] = v;
        }
      }
    }
  } else {
#pragma unroll
    for (int m = 0; m < 4; m++)
#pragma unroll
      for (int n = 0; n < 4; n++) {
        const int d = n * 16 + l15;
        const int row = rowg0 + m * 16 + l4 * 4;
        const int bb = row >> 11, ii = row & 2047;
        s16x4 o;
#pragma unroll
        for (int jj = 0; jj < 4; jj++) o[jj] = f2bf(acc[m][n][jj]);
        *(s16x4*)(vtb + ((size_t)(bb * 64 + d)) * 2048 + ii) = o;
      }
  }
}

// ---------------- GEMM (out-projection): C = A * Bm^T -----------------------
__global__ __launch_bounds__(256, 2) void gemm_bt(const short* __restrict__ A,
                                                  const short* __restrict__ Bm,
                                                  float* __restrict__ C,
                                                  int M, int N, int K) {
  __shared__ __align__(16) short Al[2][128 * 32];
  __shared__ __align__(16) short Bl[2][128 * 32];
  const int tid = threadIdx.x;
  const int lane = tid & 63;
  const int l15 = lane & 15, l4 = lane >> 4;
  const int wid = tid >> 6;
  const int wr = wid >> 1, wc = wid & 1;
  const int rowa0 = blockIdx.x * 128, rowb0 = blockIdx.y * 128;
  f32x4 acc[4][4];
#pragma unroll
  for (int m = 0; m < 4; m++)
#pragma unroll
    for (int n = 0; n < 4; n++) acc[m][n] = (f32x4){0.f, 0.f, 0.f, 0.f};

  const int sr = tid >> 2, sc = (tid & 3) * 8;
  const short* ga = A  + (size_t)(rowa0 + sr) * K + sc;
  const short* gb = Bm + (size_t)(rowb0 + sr) * K + sc;

  auto stage = [&](int buf, int k0) {
    char* la = (char*)Al[buf] + wid * 1024;
    char* lb = (char*)Bl[buf] + wid * 1024;
    async_lds16(ga + k0,                  la);
    async_lds16(ga + (size_t)64 * K + k0, la + 4096);
    async_lds16(gb + k0,                  lb);
    async_lds16(gb + (size_t)64 * K + k0, lb + 4096);
  };

  stage(0, 0);
  int cur = 0;
  for (int k0 = 0; k0 < K; k0 += 32) {
    __syncthreads();
    if (k0 + 32 < K) stage(cur ^ 1, k0 + 32);
    s16x8 af[4], bfr[4];
#pragma unroll
    for (int m = 0; m < 4; m++)
      af[m] = *(const s16x8*)&Al[cur][(wr * 64 + m * 16 + l15) * 32 + l4 * 8];
#pragma unroll
    for (int n = 0; n < 4; n++)
      bfr[n] = *(const s16x8*)&Bl[cur][(wc * 64 + n * 16 + l15) * 32 + l4 * 8];
#pragma unroll
    for (int m = 0; m < 4; m++)
#pragma unroll
      for (int n = 0; n < 4; n++)
        acc[m][n] = __builtin_amdgcn_mfma_f32_16x16x32_bf16(af[m], bfr[n], acc[m][n], 0, 0, 0);
    cur ^= 1;
  }
#pragma unroll
  for (int n = 0; n < 4; n++) {
    const int col = rowb0 + wc * 64 + n * 16 + l15;
#pragma unroll
    for (int m = 0; m < 4; m++) {
      const int row = rowa0 + wr * 64 + m * 16 + l4 * 4;
#pragma unroll
      for (int j = 0; j < 4; j++)
        C[(size_t)(row + j) * N + col] = acc[m][n][j];
    }
  }
}

// ---------------- flash attention v7: 8 waves = (q-group, key-half) ---------
// Block: 64 q-rows x 64-key tiles; wave (wq=w&3, half=w>>2) does 16q x 32keys.
// Swapped QK (lane: P[key][q=l15]); den = local adds + 2 shfl_xor; P to PV
// A-frag via 2 ds_write_b64 + 1 ds_read_b128 in XOR-swizzled per-wave buffer.
// O/den per-half partials combined once in LDS at end (static-m => exact add).
__global__ __launch_bounds__(512, 6) void attn_k(const short* __restrict__ q,
                                                 const short* __restrict__ kk,
                                                 const short* __restrict__ vt,
                                                 const unsigned short* __restrict__ btab2,
                                                 const float* __restrict__ mh,
                                                 const float* __restrict__ nkv,
                                                 const float* __restrict__ nbias,
                                                 const float* __restrict__ kscale,
                                                 short* __restrict__ aout) {
  __shared__ __align__(16) short Kl[2][64 * 64];     // 16 KB swizzled [key][d]
  __shared__ __align__(16) short Vl[2][64 * 64];     // 16 KB swizzled [d][key]
  __shared__ __align__(16) char  Pl[8][1024];        // 8 KB per-wave P (u32[16][16])
  __shared__ __align__(16) unsigned short btl[2048]; // 4 KB bf16 bias row

  float* nkn = (float*)&Pl[0][0];     // 64 f32, aliased (dead after init)
  float* nvv = (float*)&Pl[0][256];   // 64 f32

  const int tid = threadIdx.x;
  const int w = tid >> 6, lane = tid & 63;
  const int l15 = lane & 15, l4 = lane >> 4;
  const int wq = w & 3, half = w >> 2;
  const int bid = blockIdx.x;
  const int b = bid & 1, h = (bid >> 1) & 15, qt = 31 - (bid >> 5);
  const int i0 = qt * 64;
  const int nt = qt + 1;
  const int qrow0 = i0 + wq * 16;

  // stage bf16 bias row (4KB): waves 0..3
  if (tid < 256)
    async_lds16(btab2 + (size_t)h * 2048 + tid * 8, (char*)btl + w * 1024);

  const int sr = tid >> 3;                 // 0..63: full tile in one shot
  const int sb = (tid & 7) ^ (sr & 7);     // pre-swizzled source block
  const short* gk = kk + ((size_t)(b * NSEQ) + sr) * DH + sb * 8;
  const short* gv = vt + ((size_t)b * DH + sr) * NSEQ + sb * 8;

  async_lds16(gk, (char*)Kl[0] + w * 1024);
  async_lds16(gv, (char*)Vl[0] + w * 1024);

  if (w == 0) {
    float kx = nkv[lane];
    float ssn = wave_sum(kx * kx);
    nkn[lane] = kx / fmaxf(sqrtf(ssn), 1e-12f) * kscale[lane];
    nvv[lane] = nkv[64 + lane];
  }
  const short* qbase = q + (size_t)(b * NSEQ + qrow0) * DIMM + h * DH;
  s16x8 qf0 = *(const s16x8*)(qbase + (size_t)l15 * DIMM + l4 * 8);
  s16x8 qf1 = *(const s16x8*)(qbase + (size_t)l15 * DIMM + 32 + l4 * 8);
  const float m = mh[h];
  __syncthreads();   // tile-0 DMA + btl + nkn/nvv ready

  // null-token (only half==0 contributes); lane scalar den indexed by q=l15
  float den = 0.f;
  f32x4 o[4];
#pragma unroll
  for (int dg = 0; dg < 4; dg++) o[dg] = (f32x4){0.f, 0.f, 0.f, 0.f};
  if (half == 0) {
    float sn = 0.f;
#pragma unroll
    for (int j = 0; j < 8; j++)
      sn += bf2f(qf0[j]) * nkn[l4 * 8 + j] + bf2f(qf1[j]) * nkn[32 + l4 * 8 + j];
    sn += __shfl_xor(sn, 16);
    sn += __shfl_xor(sn, 32);
    const float pnc = __builtin_amdgcn_exp2f(fmaf(sn, 11.5415603f,
                                                  (nbias[h] - m) * 1.44269504f));
    den = pnc;
    float pn[4];
#pragma unroll
    for (int jj = 0; jj < 4; jj++) pn[jj] = __shfl(pnc, l4 * 4 + jj);
#pragma unroll
    for (int dg = 0; dg < 4; dg++) {
      float nv = nvv[dg * 16 + l15];
#pragma unroll
      for (int jj = 0; jj < 4; jj++) o[dg][jj] = pn[jj] * nv;
    }
  }
  __syncthreads();   // all init reads of nkn/nvv done before Pl reuse

  char* pw = (char*)Pl[w];
  const int pswz = (l15 & 3) << 4;     // XOR swizzle for this lane's q-row
  int cur = 0;

  for (int t = 0; t < nt; ++t) {
    if (t + 1 < nt) {
      const int jn = (t + 1) * 64;
      async_lds16(gk + (size_t)jn * DH, (char*)Kl[cur ^ 1] + w * 1024);
      async_lds16(gv + jn,              (char*)Vl[cur ^ 1] + w * 1024);
    }
    const int j0 = t * 64;
    // swapped QK^T over this wave's key-half: keys half*32 + kb2*16 + l15
    f32x4 s[2];
    s[0] = (f32x4){0.f, 0.f, 0.f, 0.f};
    s[1] = (f32x4){0.f, 0.f, 0.f, 0.f};
#pragma unroll
    for (int c = 0; c < 2; c++) {
#pragma unroll
      for (int kb2 = 0; kb2 < 2; kb2++) {
        const int key = half * 32 + kb2 * 16 + l15;
        s16x8 kf = *(const s16x8*)((const char*)Kl[cur] + key * 128 +
                                   ((((c << 2) + l4) ^ (key & 7)) << 4));
        s[kb2] = __builtin_amdgcn_mfma_f32_16x16x32_bf16(kf, c == 0 ? qf0 : qf1, s[kb2], 0, 0, 0);
      }
    }
    // softmax: q = qrow0+l15; key = j0 + half*32 + kb2*16 + l4*4 + jj
    float p[2][4];
    float loc = 0.f;
#pragma unroll
    for (int kb2 = 0; kb2 < 2; kb2++) {
#pragma unroll
      for (int jj = 0; jj < 4; jj++) {
        const int rel = (qrow0 + l15) - (j0 + half * 32 + kb2 * 16 + l4 * 4 + jj);
        const float bb = bf2f((short)btl[rel & 2047]);
        const float sv = fmaf(s[kb2][jj], 11.5415603f, bb);
        const float pp = (rel >= 0) ? __builtin_amdgcn_exp2f(sv) : 0.f;
        p[kb2][jj] = pp;
        loc += pp;
      }
    }
    loc += __shfl_xor(loc, 16);
    loc += __shfl_xor(loc, 32);
    den += loc;
    // pack P -> per-wave swizzled LDS (u32[16][16], row = q, 2B/key)
    {
      uint2 w0v, w1v;
      w0v.x = cvtpk_bf16(p[0][0], p[0][1]);
      w0v.y = cvtpk_bf16(p[0][2], p[0][3]);
      w1v.x = cvtpk_bf16(p[1][0], p[1][1]);
      w1v.y = cvtpk_bf16(p[1][2], p[1][3]);
      *(uint2*)(pw + l15 * 64 + (((l4 << 3)      ) ^ pswz)) = w0v;
      *(uint2*)(pw + l15 * 64 + (((l4 << 3) + 32 ) ^ pswz)) = w1v;
    }
    // PV: A-frag = this wave's P rows (q=l15, local keys l4*8..+7)
    s16x8 pf = *(const s16x8*)(pw + l15 * 64 + (((l4 << 4)) ^ pswz));
    {
      const int slice = half * 4 + l4;
#pragma unroll
      for (int dg = 0; dg < 4; dg++) {
        const int d = dg * 16 + l15;
        s16x8 vf = *(const s16x8*)((const char*)Vl[cur] + d * 128 +
                                   ((slice ^ (d & 7)) << 4));
        o[dg] = __builtin_amdgcn_mfma_f32_16x16x32_bf16(pf, vf, o[dg], 0, 0, 0);
      }
    }
    __syncthreads();
    cur ^= 1;
  }

  // ---- combine halves in LDS (Kl: O-partials, btl: den-partials) ----
  if (half == 1) {
    float* st = (float*)Kl + wq * 1024;
#pragma unroll
    for (int dg = 0; dg < 4; dg++)
#pragma unroll
      for (int jj = 0; jj < 4; jj++)
        st[(l4 * 4 + jj) * 64 + dg * 16 + l15] = o[dg][jj];
    if (l4 == 0) ((float*)btl)[wq * 16 + l15] = den;
  }
  __syncthreads();
  if (half == 0) {
    float* st = (float*)Kl + wq * 1024;
    float denj[4];
#pragma unroll
    for (int jj = 0; jj < 4; jj++)
      denj[jj] = __shfl(den, l4 * 4 + jj) + ((float*)btl)[wq * 16 + l4 * 4 + jj];
    // per-wave ob staging in Vl (dead), then coalesced bf16 store
    float* ob = (float*)Vl + wq * 1024;
#pragma unroll
    for (int dg = 0; dg < 4; dg++)
#pragma unroll
      for (int jj = 0; jj < 4; jj++)
        ob[(l4 * 4 + jj) * 64 + dg * 16 + l15] =
            (o[dg][jj] + st[(l4 * 4 + jj) * 64 + dg * 16 + l15]) / denj[jj];
    const int orow = lane >> 2, oc = (lane & 3) * 16;
    const float* srcp = ob + orow * 64 + oc;
    s16x8 r0, r1;
#pragma unroll
    for (int j = 0; j < 8; j++) { r0[j] = f2bf(srcp[j]); r1[j] = f2bf(srcp[8 + j]); }
    short* gout = aout + (size_t)(b * NSEQ + i0 + wq * 16 + orow) * DIMM + h * DH + oc;
    *(s16x8*)gout = r0;
    *(s16x8*)(gout + 8) = r1;
  }
}

// ---------------- final row LayerNorm ---------------------------------------
__global__ __launch_bounds__(256) void final_ln_k(const float* __restrict__ in,
                                                  const float* __restrict__ gamma,
                                                  float* __restrict__ of) {
  const int r = blockIdx.x, t = threadIdx.x;
  float4 x = *(const float4*)(in + (size_t)r * 1024 + t * 4);
  float v[4] = {x.x, x.y, x.z, x.w};
  float s  = v[0] + v[1] + v[2] + v[3];
  float ss = v[0]*v[0] + v[1]*v[1] + v[2]*v[2] + v[3]*v[3];
  s = wave_sum(s); ss = wave_sum(ss);
  __shared__ float rb[8];
  const int w = t >> 6, ln = t & 63;
  if (ln == 0) { rb[w] = s; rb[4 + w] = ss; }
  __syncthreads();
  s  = rb[0] + rb[1] + rb[2] + rb[3];
  ss = rb[4] + rb[5] + rb[6] + rb[7];
  const float mean = s * (1.f / 1024.f);
  const float inv  = rsqrtf(ss * (1.f / 1024.f) - mean * mean + 1e-5f);
  float4 gx = *(const float4*)(gamma + t * 4);
  float gg[4] = {gx.x, gx.y, gx.z, gx.w};
  float4 o;
  o.x = (v[0] - mean) * inv * gg[0];
  o.y = (v[1] - mean) * inv * gg[1];
  o.z = (v[2] - mean) * inv * gg[2];
  o.w = (v[3] - mean) * inv * gg[3];
  *(float4*)(of + (size_t)r * 1024 + t * 4) = o;
}

// ---------------------------------------------------------------------------
extern "C" void kernel_launch(void* const* d_in, const int* in_sizes, int n_in,
                              void* d_out, int out_size, void* d_ws, size_t ws_size,
                              hipStream_t stream) {
  const float* x       = (const float*)d_in[0];
  const float* g_norm  = (const float*)d_in[2];
  const float* Wq      = (const float*)d_in[3];
  const float* Wkv     = (const float*)d_in[4];
  const float* q_scale = (const float*)d_in[5];
  const float* k_scale = (const float*)d_in[6];
  const float* null_kv = (const float*)d_in[7];
  const float* nbias   = (const float*)d_in[8];
  const float* w0      = (const float*)d_in[9];
  const float* b0      = (const float*)d_in[10];
  const float* g0      = (const float*)d_in[11];
  const float* w1      = (const float*)d_in[12];
  const float* b1      = (const float*)d_in[13];
  const float* g1      = (const float*)d_in[14];
  const float* w2      = (const float*)d_in[15];
  const float* b2      = (const float*)d_in[16];
  const float* Wout    = (const float*)d_in[17];
  const float* g_out   = (const float*)d_in[18];

  char* p = (char*)d_ws;
  auto alloc = [&](size_t bytes) {
    char* r = p; p += (bytes + 255) & ~(size_t)255; return r;
  };
  short* xn     = (short*)alloc((size_t)4096 * 1024 * 2);
  short* wqkvT  = (short*)alloc((size_t)1152 * 1024 * 2);
  short* w1T    = (short*)alloc((size_t)1024 * 1024 * 2);
  short* woT    = (short*)alloc((size_t)1024 * 1024 * 2);
  short* qb     = (short*)alloc((size_t)4096 * 1024 * 2);
  short* kbuf   = (short*)alloc((size_t)2 * NSEQ * DH * 2);
  short* vtb    = (short*)alloc((size_t)2 * DH * NSEQ * 2);
  short* h0     = (short*)alloc((size_t)2048 * 1024 * 2);
  float* btab   = (float*)alloc((size_t)16 * NSEQ * 4);
  unsigned short* btab2 = (unsigned short*)alloc((size_t)16 * NSEQ * 2);
  float* mh     = (float*)alloc(16 * 4);
  float* opre   = (float*)alloc((size_t)4096 * 1024 * 4);
  // time-sliced aliases:
  float* h1t  = opre;            // bias-MLP h1 pre-LN (dead before out-proj)
  short* aout = xn;              // attn output (xn dead after qkv gemm)

  prep_k<<<9344, 256, 0, stream>>>(x, g_norm, w0, b0, g0, Wq, Wkv, w1, Wout,
                                   xn, h0, wqkvT, w1T, woT);
  gemm2_k<<<416, 256, 0, stream>>>(xn, wqkvT, h0, w1T, h1t, b1,
                                   q_scale, k_scale, qb, kbuf, vtb);
  btab_k<<<2048, 256, 0, stream>>>(h1t, g1, w2, b2, btab);
  bmax_k<<<16, 256, 0, stream>>>(btab, nbias, btab2, mh);
  attn_k<<<dim3(1024), 512, 0, stream>>>(qb, kbuf, vtb, btab2, mh, null_kv, nbias,
                                         k_scale, aout);
  gemm_bt<<<dim3(32, 8), 256, 0, stream>>>(aout, woT, opre, 4096, 1024, 1024);
  final_ln_k<<<4096, 256, 0, stream>>>(opre, g_out, (float*)d_out);
}